// Round 2
// baseline (2377.808 us; speedup 1.0000x reference)
//
#include <hip/hip_runtime.h>
#include <hip/hip_bf16.h>
#include <math.h>

typedef __attribute__((ext_vector_type(8))) short bf16x8s;
typedef __attribute__((ext_vector_type(4))) float f32x4;

#define SEQ 2048
#define NTOK 8192

static __device__ __forceinline__ float bf2f(unsigned short u) {
  union { unsigned int i; float f; } c; c.i = ((unsigned int)u) << 16; return c.f;
}
static __device__ __forceinline__ unsigned short f2bf(float f) {
  union { float f; unsigned int i; } c; c.f = f;
  unsigned int x = c.i;
  return (unsigned short)((x + 0x7FFFu + ((x >> 16) & 1u)) >> 16);
}

// ---------------------------------------------------------------- x cast fp32 -> bf16
__global__ __launch_bounds__(256) void castx_k(const float* __restrict__ in,
                                               unsigned short* __restrict__ out, int n4) {
  int i = blockIdx.x * 256 + threadIdx.x;
  if (i >= n4) return;
  float4 v = ((const float4*)in)[i];
  ushort4 o;
  o.x = f2bf(v.x); o.y = f2bf(v.y); o.z = f2bf(v.z); o.w = f2bf(v.w);
  ((ushort4*)out)[i] = o;
}

// ---------------------------------------------------------------- transpose fp32 -> bf16
// out[c][r] = bf16(in[r][c]), R x C -> C x R
__global__ void transpose_k(const float* __restrict__ in,
                            unsigned short* __restrict__ out, int R, int C) {
  __shared__ unsigned short tile[32][33];
  int c0 = blockIdx.x * 32, r0 = blockIdx.y * 32;
  int tx = threadIdx.x, ty = threadIdx.y;
  for (int i = ty; i < 32; i += 8)
    tile[i][tx] = f2bf(in[(size_t)(r0 + i) * C + c0 + tx]);
  __syncthreads();
  for (int i = ty; i < 32; i += 8)
    out[(size_t)(c0 + i) * R + r0 + tx] = tile[tx][i];
}

// ---------------------------------------------------------------- Wab concat (fp32)
__global__ void build_wab(const float* __restrict__ Wa,
                          const float* __restrict__ Wb,
                          float* __restrict__ Wab) {
  int i = blockIdx.x * 256 + threadIdx.x;  // 1024*32
  int k = i >> 5, j = i & 31;
  Wab[i] = (j < 16) ? Wa[k * 16 + j] : Wb[k * 16 + (j - 16)];
}

// ---------------------------------------------------------------- MFMA GEMM
// C[M,N] = A[M,K] * Bt[N,K]^T   (bf16 in, fp32 accum, bf16 or fp32 out)
// 128x128 tile, BK=32, 256 threads (4 waves, each 64x64).
#define BKP 56  // padded LDS leading dim: 112B rows (16B-aligned), 2-way bank alias (free)
template<bool F32OUT>
__global__ __launch_bounds__(256) void gemm_bt(const unsigned short* __restrict__ A,
                                               const unsigned short* __restrict__ Bt,
                                               void* __restrict__ Cv,
                                               int M, int N, int K) {
  __shared__ __align__(16) unsigned short As[128 * BKP];
  __shared__ __align__(16) unsigned short Bs[128 * BKP];
  int tiles_n = N >> 7;
  int tm = blockIdx.x / tiles_n, tn = blockIdx.x % tiles_n;
  int m0 = tm << 7, n0 = tn << 7;
  int tid = threadIdx.x;
  int wave = tid >> 6, lane = tid & 63;
  int wm = wave >> 1, wn = wave & 1;
  int r = lane & 15, qd = lane >> 4;

  f32x4 acc[4][4];
#pragma unroll
  for (int mi = 0; mi < 4; mi++)
#pragma unroll
    for (int ni = 0; ni < 4; ni++) acc[mi][ni] = (f32x4){0.f, 0.f, 0.f, 0.f};

  for (int k0 = 0; k0 < K; k0 += 32) {
#pragma unroll
    for (int i = 0; i < 2; ++i) {
      int cc = tid + (i << 8);
      int row = cc >> 2, seg = cc & 3;
      uint4 av = *(const uint4*)&A[(size_t)(m0 + row) * K + k0 + (seg << 3)];
      *(uint4*)&As[row * BKP + (seg << 3)] = av;
      uint4 bv = *(const uint4*)&Bt[(size_t)(n0 + row) * K + k0 + (seg << 3)];
      *(uint4*)&Bs[row * BKP + (seg << 3)] = bv;
    }
    __syncthreads();
    bf16x8s af[4], bfr[4];
#pragma unroll
    for (int mi = 0; mi < 4; mi++)
      af[mi] = *(const bf16x8s*)&As[(wm * 64 + mi * 16 + r) * BKP + qd * 8];
#pragma unroll
    for (int ni = 0; ni < 4; ni++)
      bfr[ni] = *(const bf16x8s*)&Bs[(wn * 64 + ni * 16 + r) * BKP + qd * 8];
#pragma unroll
    for (int mi = 0; mi < 4; mi++)
#pragma unroll
      for (int ni = 0; ni < 4; ni++)
        acc[mi][ni] = __builtin_amdgcn_mfma_f32_16x16x32_bf16(af[mi], bfr[ni], acc[mi][ni], 0, 0, 0);
    __syncthreads();
  }
  // epilogue: D row = qd*4+reg, col = r  (verified C/D layout m89)
#pragma unroll
  for (int mi = 0; mi < 4; mi++)
#pragma unroll
    for (int ni = 0; ni < 4; ni++)
#pragma unroll
      for (int reg = 0; reg < 4; reg++) {
        int m = m0 + wm * 64 + mi * 16 + qd * 4 + reg;
        int n = n0 + wn * 64 + ni * 16 + r;
        if (F32OUT) ((float*)Cv)[(size_t)m * N + n] = acc[mi][ni][reg];
        else ((unsigned short*)Cv)[(size_t)m * N + n] = f2bf(acc[mi][ni][reg]);
      }
}

// ---------------------------------------------------------------- alpha/beta (pure fp32)
// out[m][j] = sigmoid(sum_k x[m][k]*Wab[k][j] + bias[j]), j in [0,32)
__global__ __launch_bounds__(256) void ab_kernel(const float* __restrict__ x,
                                                 const float* __restrict__ Wab,
                                                 const float* __restrict__ ba,
                                                 const float* __restrict__ bb,
                                                 float* __restrict__ alphaF,
                                                 float* __restrict__ betaF) {
  __shared__ __align__(16) float xs[8 * 1024];  // 32 KB
  int tid = threadIdx.x;
  int m0 = blockIdx.x * 8;
  const float* xg = x + (size_t)m0 * 1024;
  for (int i = tid; i < 2048; i += 256)
    *(float4*)&xs[i * 4] = *(const float4*)&xg[i * 4];
  __syncthreads();
  int mi = tid >> 5, j = tid & 31;
  float acc = 0.f;
#pragma unroll 8
  for (int k = 0; k < 1024; ++k)
    acc += xs[mi * 1024 + k] * Wab[k * 32 + j];
  float bias = (j < 16) ? ba[j] : bb[j - 16];
  float s = 1.f / (1.f + expf(-(acc + bias)));
  int m = m0 + mi;
  if (j < 16) alphaF[m * 16 + j] = s;
  else        betaF[m * 16 + (j - 16)] = s;
}

// ---------------------------------------------------------------- L2 norm q,k (in-place bf16)
__global__ __launch_bounds__(256) void l2norm_k(unsigned short* __restrict__ qkv) {
  int id = blockIdx.x * 4 + (threadIdx.x >> 6);  // 262144 chunks
  int lane = threadIdx.x & 63;
  int which = id >> 17;  // 0 => q, 1 => k
  int mh = id & 131071;
  int m = mh >> 4, h = mh & 15;
  size_t off = (size_t)m * 3072 + (size_t)which * 1024 + h * 64 + lane;
  float v = bf2f(qkv[off]);
  float ss = v * v;
#pragma unroll
  for (int s = 1; s < 64; s <<= 1) ss += __shfl_xor(ss, s);
  float scale = 1.0f / fmaxf(sqrtf(ss), 1e-12f);
  qkv[off] = f2bf(v * scale);
}

// ---------------------------------------------------------------- scan
// one block per (b,h); state S[d][e] 64x64 fp32, thread (e=tid>>2, g=tid&3)
// owns S[16g..16g+16)[e] in registers.
__global__ __launch_bounds__(256) void scan_k(const unsigned short* __restrict__ qkv,
                                              const float* __restrict__ alphaF,
                                              const float* __restrict__ betaF,
                                              unsigned short* __restrict__ y) {
  int b = blockIdx.x >> 4, h = blockIdx.x & 15;
  int tid = threadIdx.x;
  int e = tid >> 2, g = tid & 3;
  __shared__ float lq[64], lk[64], lv[64], lab[2];
  float S[16];
#pragma unroll
  for (int j = 0; j < 16; j++) S[j] = 0.f;
  const unsigned short* rowbase = qkv + (size_t)b * SEQ * 3072 + h * 64;

  unsigned short pre = 0; float preab = 0.f;
  {
    const unsigned short* row = rowbase;
    if (tid < 64)        pre = row[tid];
    else if (tid < 128)  pre = row[1024 + (tid - 64)];
    else if (tid < 192)  pre = row[2048 + (tid - 128)];
    else if (tid == 192) preab = alphaF[(size_t)(b * SEQ) * 16 + h];
    else if (tid == 193) preab = betaF[(size_t)(b * SEQ) * 16 + h];
  }
  for (int t = 0; t < SEQ; ++t) {
    if (tid < 64)        lq[tid] = bf2f(pre);
    else if (tid < 128)  lk[tid - 64] = bf2f(pre);
    else if (tid < 192)  lv[tid - 128] = bf2f(pre);
    else if (tid == 192) lab[0] = preab;
    else if (tid == 193) lab[1] = preab;
    __syncthreads();
    if (t + 1 < SEQ) {  // prefetch next step while computing this one
      const unsigned short* row = rowbase + (size_t)(t + 1) * 3072;
      if (tid < 64)        pre = row[tid];
      else if (tid < 128)  pre = row[1024 + (tid - 64)];
      else if (tid < 192)  pre = row[2048 + (tid - 128)];
      else if (tid == 192) preab = alphaF[(size_t)(b * SEQ + t + 1) * 16 + h];
      else if (tid == 193) preab = betaF[(size_t)(b * SEQ + t + 1) * 16 + h];
    }
    float a_t = lab[0], b_t = lab[1];
    float kk[16], qq[16];
#pragma unroll
    for (int j = 0; j < 16; j++) { kk[j] = lk[g * 16 + j]; qq[j] = lq[g * 16 + j]; }
    float pred = 0.f, qs = 0.f, kq = 0.f;
#pragma unroll
    for (int j = 0; j < 16; j++) {
      pred += S[j] * kk[j];
      qs   += S[j] * qq[j];
      kq   += kk[j] * qq[j];
    }
    pred += __shfl_xor(pred, 1); pred += __shfl_xor(pred, 2);
    qs   += __shfl_xor(qs, 1);   qs   += __shfl_xor(qs, 2);
    kq   += __shfl_xor(kq, 1);   kq   += __shfl_xor(kq, 2);
    float err = lv[e] - pred;
    float be = b_t * err;
#pragma unroll
    for (int j = 0; j < 16; j++) S[j] = a_t * S[j] + kk[j] * be;
    if (g == 0) {
      float outv = a_t * qs + be * kq;  // q . S_new (fused)
      y[(size_t)(b * SEQ + t) * 1024 + h * 64 + e] = f2bf(outv);
    }
    __syncthreads();
  }
}

// ---------------------------------------------------------------- rmsnorm*gate
__global__ __launch_bounds__(256) void rmsgate_k(const unsigned short* __restrict__ y,
                                                 const unsigned short* __restrict__ gl,
                                                 const float* __restrict__ gnorm,
                                                 unsigned short* __restrict__ z) {
  __shared__ float red[4];
  int row = blockIdx.x, tid = threadIdx.x;
  size_t base = (size_t)row * 1024 + tid * 4;
  uint2 yv = *(const uint2*)&y[base];
  float f0 = bf2f((unsigned short)(yv.x & 0xffff)), f1 = bf2f((unsigned short)(yv.x >> 16));
  float f2 = bf2f((unsigned short)(yv.y & 0xffff)), f3 = bf2f((unsigned short)(yv.y >> 16));
  float ss = f0 * f0 + f1 * f1 + f2 * f2 + f3 * f3;
#pragma unroll
  for (int s = 1; s < 64; s <<= 1) ss += __shfl_xor(ss, s);
  if ((tid & 63) == 0) red[tid >> 6] = ss;
  __syncthreads();
  ss = red[0] + red[1] + red[2] + red[3];
  float rms = rsqrtf(ss * (1.0f / 1024.0f) + 1e-5f);
  uint2 gv = *(const uint2*)&gl[base];
  float4 gn = *(const float4*)&gnorm[tid * 4];
  float g[4] = {bf2f((unsigned short)(gv.x & 0xffff)), bf2f((unsigned short)(gv.x >> 16)),
                bf2f((unsigned short)(gv.y & 0xffff)), bf2f((unsigned short)(gv.y >> 16))};
  float gnv[4] = {gn.x, gn.y, gn.z, gn.w};
  float fv[4] = {f0, f1, f2, f3};
  unsigned short o[4];
#pragma unroll
  for (int jj = 0; jj < 4; jj++) {
    float gate = g[jj] / (1.f + expf(-g[jj]));  // silu
    o[jj] = f2bf(fv[jj] * rms * gnv[jj] * gate);
  }
  uint2 ov;
  ov.x = (unsigned int)o[0] | ((unsigned int)o[1] << 16);
  ov.y = (unsigned int)o[2] | ((unsigned int)o[3] << 16);
  *(uint2*)&z[base] = ov;
}

// ---------------------------------------------------------------- launch
extern "C" void kernel_launch(void* const* d_in, const int* in_sizes, int n_in,
                              void* d_out, int out_size, void* d_ws, size_t ws_size,
                              hipStream_t stream) {
  const float* x     = (const float*)d_in[0];
  const float* Wq    = (const float*)d_in[1];
  const float* Wk    = (const float*)d_in[2];
  const float* Wv    = (const float*)d_in[3];
  const float* Wa    = (const float*)d_in[4];
  const float* ba    = (const float*)d_in[5];
  const float* Wb    = (const float*)d_in[6];
  const float* bb    = (const float*)d_in[7];
  const float* Wg    = (const float*)d_in[8];
  const float* Wo    = (const float*)d_in[9];
  const float* gnorm = (const float*)d_in[10];
  float* out = (float*)d_out;

  unsigned short* xbf    = (unsigned short*)d_ws;                 // 8192*1024
  unsigned short* Bt_qkv = xbf + (size_t)NTOK * 1024;             // 3072*1024
  unsigned short* Bt_g   = Bt_qkv + (size_t)3072 * 1024;          // 1024*1024
  unsigned short* Bt_o   = Bt_g + (size_t)1024 * 1024;            // 1024*1024
  unsigned short* qkv    = Bt_o + (size_t)1024 * 1024;            // 8192*3072
  unsigned short* gatelin= qkv + (size_t)NTOK * 3072;             // 8192*1024
  unsigned short* ybuf   = gatelin + (size_t)NTOK * 1024;         // 8192*1024
  float* Wab             = (float*)(ybuf + (size_t)NTOK * 1024);  // 1024*32
  float* alphaF          = Wab + 1024 * 32;                       // 8192*16
  float* betaF           = alphaF + (size_t)NTOK * 16;            // 8192*16
  unsigned short* zbuf   = xbf;  // alias: xbf dead after gate GEMM

  castx_k<<<NTOK * 1024 / 4 / 256, 256, 0, stream>>>(x, xbf, NTOK * 1024 / 4);
  dim3 tb(32, 8);
  transpose_k<<<dim3(32, 32), tb, 0, stream>>>(Wq, Bt_qkv, 1024, 1024);
  transpose_k<<<dim3(32, 32), tb, 0, stream>>>(Wk, Bt_qkv + (size_t)1024 * 1024, 1024, 1024);
  transpose_k<<<dim3(32, 32), tb, 0, stream>>>(Wv, Bt_qkv + (size_t)2048 * 1024, 1024, 1024);
  transpose_k<<<dim3(32, 32), tb, 0, stream>>>(Wg, Bt_g, 1024, 1024);
  transpose_k<<<dim3(32, 32), tb, 0, stream>>>(Wo, Bt_o, 1024, 1024);
  build_wab<<<128, 256, 0, stream>>>(Wa, Wb, Wab);

  gemm_bt<false><<<(NTOK / 128) * (3072 / 128), 256, 0, stream>>>(xbf, Bt_qkv, qkv, NTOK, 3072, 1024);
  ab_kernel<<<NTOK / 8, 256, 0, stream>>>(x, Wab, ba, bb, alphaF, betaF);
  l2norm_k<<<65536, 256, 0, stream>>>(qkv);
  gemm_bt<false><<<(NTOK / 128) * (1024 / 128), 256, 0, stream>>>(xbf, Bt_g, gatelin, NTOK, 1024, 1024);
  scan_k<<<64, 256, 0, stream>>>(qkv, alphaF, betaF, ybuf);
  rmsgate_k<<<NTOK, 256, 0, stream>>>(ybuf, gatelin, gnorm, zbuf);
  gemm_bt<true><<<(NTOK / 128) * (1024 / 128), 256, 0, stream>>>(zbuf, Bt_o, out, NTOK, 1024, 1024);
}

// Round 3
// 904.584 us; speedup vs baseline: 2.6286x; 2.6286x over previous
//
#include <hip/hip_runtime.h>
#include <hip/hip_bf16.h>
#include <math.h>

typedef __attribute__((ext_vector_type(8))) short bf16x8s;
typedef __attribute__((ext_vector_type(4))) float f32x4;

#define SEQ 2048
#define NTOK 8192

static __device__ __forceinline__ float bf2f(unsigned short u) {
  union { unsigned int i; float f; } c; c.i = ((unsigned int)u) << 16; return c.f;
}
static __device__ __forceinline__ unsigned short f2bf(float f) {
  union { float f; unsigned int i; } c; c.f = f;
  unsigned int x = c.i;
  return (unsigned short)((x + 0x7FFFu + ((x >> 16) & 1u)) >> 16);
}

// ---------------------------------------------------------------- x cast fp32 -> bf16
__global__ __launch_bounds__(256) void castx_k(const float* __restrict__ in,
                                               unsigned short* __restrict__ out, int n4) {
  int i = blockIdx.x * 256 + threadIdx.x;
  if (i >= n4) return;
  float4 v = ((const float4*)in)[i];
  ushort4 o;
  o.x = f2bf(v.x); o.y = f2bf(v.y); o.z = f2bf(v.z); o.w = f2bf(v.w);
  ((ushort4*)out)[i] = o;
}

// ---------------------------------------------------------------- transpose fp32 -> bf16
__global__ void transpose_k(const float* __restrict__ in,
                            unsigned short* __restrict__ out, int R, int C) {
  __shared__ unsigned short tile[32][33];
  int c0 = blockIdx.x * 32, r0 = blockIdx.y * 32;
  int tx = threadIdx.x, ty = threadIdx.y;
  for (int i = ty; i < 32; i += 8)
    tile[i][tx] = f2bf(in[(size_t)(r0 + i) * C + c0 + tx]);
  __syncthreads();
  for (int i = ty; i < 32; i += 8)
    out[(size_t)(c0 + i) * R + r0 + tx] = tile[tx][i];
}

// ---------------------------------------------------------------- Wab concat (fp32)
__global__ void build_wab(const float* __restrict__ Wa,
                          const float* __restrict__ Wb,
                          float* __restrict__ Wab) {
  int i = blockIdx.x * 256 + threadIdx.x;  // 1024*32
  int k = i >> 5, j = i & 31;
  Wab[i] = (j < 16) ? Wa[k * 16 + j] : Wb[k * 16 + (j - 16)];
}

// ---------------------------------------------------------------- MFMA GEMM
// C[M,N] = A[M,K] * Bt[N,K]^T   (bf16 in, fp32 accum, bf16 or fp32 out)
#define BKP 56
template<bool F32OUT>
__global__ __launch_bounds__(256) void gemm_bt(const unsigned short* __restrict__ A,
                                               const unsigned short* __restrict__ Bt,
                                               void* __restrict__ Cv,
                                               int M, int N, int K) {
  __shared__ __align__(16) unsigned short As[128 * BKP];
  __shared__ __align__(16) unsigned short Bs[128 * BKP];
  int tiles_n = N >> 7;
  int tm = blockIdx.x / tiles_n, tn = blockIdx.x % tiles_n;
  int m0 = tm << 7, n0 = tn << 7;
  int tid = threadIdx.x;
  int wave = tid >> 6, lane = tid & 63;
  int wm = wave >> 1, wn = wave & 1;
  int r = lane & 15, qd = lane >> 4;

  f32x4 acc[4][4];
#pragma unroll
  for (int mi = 0; mi < 4; mi++)
#pragma unroll
    for (int ni = 0; ni < 4; ni++) acc[mi][ni] = (f32x4){0.f, 0.f, 0.f, 0.f};

  for (int k0 = 0; k0 < K; k0 += 32) {
#pragma unroll
    for (int i = 0; i < 2; ++i) {
      int cc = tid + (i << 8);
      int row = cc >> 2, seg = cc & 3;
      uint4 av = *(const uint4*)&A[(size_t)(m0 + row) * K + k0 + (seg << 3)];
      *(uint4*)&As[row * BKP + (seg << 3)] = av;
      uint4 bv = *(const uint4*)&Bt[(size_t)(n0 + row) * K + k0 + (seg << 3)];
      *(uint4*)&Bs[row * BKP + (seg << 3)] = bv;
    }
    __syncthreads();
    bf16x8s af[4], bfr[4];
#pragma unroll
    for (int mi = 0; mi < 4; mi++)
      af[mi] = *(const bf16x8s*)&As[(wm * 64 + mi * 16 + r) * BKP + qd * 8];
#pragma unroll
    for (int ni = 0; ni < 4; ni++)
      bfr[ni] = *(const bf16x8s*)&Bs[(wn * 64 + ni * 16 + r) * BKP + qd * 8];
#pragma unroll
    for (int mi = 0; mi < 4; mi++)
#pragma unroll
      for (int ni = 0; ni < 4; ni++)
        acc[mi][ni] = __builtin_amdgcn_mfma_f32_16x16x32_bf16(af[mi], bfr[ni], acc[mi][ni], 0, 0, 0);
    __syncthreads();
  }
#pragma unroll
  for (int mi = 0; mi < 4; mi++)
#pragma unroll
    for (int ni = 0; ni < 4; ni++)
#pragma unroll
      for (int reg = 0; reg < 4; reg++) {
        int m = m0 + wm * 64 + mi * 16 + qd * 4 + reg;
        int n = n0 + wn * 64 + ni * 16 + r;
        if (F32OUT) ((float*)Cv)[(size_t)m * N + n] = acc[mi][ni][reg];
        else ((unsigned short*)Cv)[(size_t)m * N + n] = f2bf(acc[mi][ni][reg]);
      }
}

// ---------------------------------------------------------------- alpha/beta (pure fp32)
__global__ __launch_bounds__(256) void ab_kernel(const float* __restrict__ x,
                                                 const float* __restrict__ Wab,
                                                 const float* __restrict__ ba,
                                                 const float* __restrict__ bb,
                                                 float* __restrict__ alphaF,
                                                 float* __restrict__ betaF) {
  __shared__ __align__(16) float xs[8 * 1024];  // 32 KB
  int tid = threadIdx.x;
  int m0 = blockIdx.x * 8;
  const float* xg = x + (size_t)m0 * 1024;
  for (int i = tid; i < 2048; i += 256)
    *(float4*)&xs[i * 4] = *(const float4*)&xg[i * 4];
  __syncthreads();
  int mi = tid >> 5, j = tid & 31;
  float acc = 0.f;
#pragma unroll 8
  for (int k = 0; k < 1024; ++k)
    acc += xs[mi * 1024 + k] * Wab[k * 32 + j];
  float bias = (j < 16) ? ba[j] : bb[j - 16];
  float s = 1.f / (1.f + expf(-(acc + bias)));
  int m = m0 + mi;
  if (j < 16) alphaF[m * 16 + j] = s;
  else        betaF[m * 16 + (j - 16)] = s;
}

// ---------------------------------------------------------------- L2 norm q,k (in-place bf16)
__global__ __launch_bounds__(256) void l2norm_k(unsigned short* __restrict__ qkv) {
  int id = blockIdx.x * 4 + (threadIdx.x >> 6);
  int lane = threadIdx.x & 63;
  int which = id >> 17;
  int mh = id & 131071;
  int m = mh >> 4, h = mh & 15;
  size_t off = (size_t)m * 3072 + (size_t)which * 1024 + h * 64 + lane;
  float v = bf2f(qkv[off]);
  float ss = v * v;
#pragma unroll
  for (int s = 1; s < 64; s <<= 1) ss += __shfl_xor(ss, s);
  float scale = 1.0f / fmaxf(sqrtf(ss), 1e-12f);
  qkv[off] = f2bf(v * scale);
}

// ---------------------------------------------------------------- scan (restructured)
// Column decomposition: S[:,e] evolves independently per e.
// Grid: 256 blocks = (b*16+h)*4 + eq, eq covers e0=eq*16 .. +16.
// Thread: el = tid>>4 (local e), g = tid&15 (d-group of 4). State: 4 fp32 regs.
// Chunked: T=64 steps staged in LDS (fp32), double-buffered, 1 barrier/chunk.
#define TCH 64
#define LKOF 0
#define LQOF 4096
#define LVOF 8192
#define LAOF 9216
#define LBOF 9280
#define BUFSZ 9344

struct Pref { uint4 k0, k1, q0, q1, v; float ab; };

static __device__ __forceinline__ Pref stage_load(const unsigned short* __restrict__ qkv,
                                                  const float* __restrict__ alphaF,
                                                  const float* __restrict__ betaF,
                                                  int b, int h, int e0, int t0, int tid) {
  Pref p; p.v = (uint4){0, 0, 0, 0}; p.ab = 0.f;
  int trow = tid >> 3, l8 = tid & 7;
  const unsigned short* base = qkv + (size_t)(b * SEQ + t0) * 3072 + h * 64;
  p.q0 = *(const uint4*)(base + (size_t)trow * 3072 + l8 * 8);
  p.q1 = *(const uint4*)(base + (size_t)(trow + 32) * 3072 + l8 * 8);
  p.k0 = *(const uint4*)(base + (size_t)trow * 3072 + 1024 + l8 * 8);
  p.k1 = *(const uint4*)(base + (size_t)(trow + 32) * 3072 + 1024 + l8 * 8);
  if (tid < 128) {
    int tv = tid >> 1, hv = tid & 1;
    p.v = *(const uint4*)(base + (size_t)tv * 3072 + 2048 + e0 + hv * 8);
  } else if (tid < 192) {
    p.ab = alphaF[(size_t)(b * SEQ + t0 + (tid - 128)) * 16 + h];
  } else {
    p.ab = betaF[(size_t)(b * SEQ + t0 + (tid - 192)) * 16 + h];
  }
  return p;
}

static __device__ __forceinline__ void store8f(float* p, uint4 v) {
  float4 a, b;
  a.x = bf2f((unsigned short)(v.x & 0xffff)); a.y = bf2f((unsigned short)(v.x >> 16));
  a.z = bf2f((unsigned short)(v.y & 0xffff)); a.w = bf2f((unsigned short)(v.y >> 16));
  b.x = bf2f((unsigned short)(v.z & 0xffff)); b.y = bf2f((unsigned short)(v.z >> 16));
  b.z = bf2f((unsigned short)(v.w & 0xffff)); b.w = bf2f((unsigned short)(v.w >> 16));
  *(float4*)p = a; *(float4*)(p + 4) = b;
}

static __device__ __forceinline__ void stage_write(float* __restrict__ bb, const Pref& p, int tid) {
  int trow = tid >> 3, l8 = tid & 7;
  store8f(&bb[LQOF + trow * 64 + l8 * 8], p.q0);
  store8f(&bb[LQOF + (trow + 32) * 64 + l8 * 8], p.q1);
  store8f(&bb[LKOF + trow * 64 + l8 * 8], p.k0);
  store8f(&bb[LKOF + (trow + 32) * 64 + l8 * 8], p.k1);
  if (tid < 128) {
    store8f(&bb[LVOF + (tid >> 1) * 16 + (tid & 1) * 8], p.v);
  } else if (tid < 192) {
    bb[LAOF + (tid - 128)] = p.ab;
  } else {
    bb[LBOF + (tid - 192)] = p.ab;
  }
}

__global__ __launch_bounds__(256) void scan_k(const unsigned short* __restrict__ qkv,
                                              const float* __restrict__ alphaF,
                                              const float* __restrict__ betaF,
                                              unsigned short* __restrict__ y) {
  __shared__ float sm[2 * BUFSZ];  // ~74.8 KB
  int bh = blockIdx.x >> 2;
  int b = bh >> 4, h = bh & 15;
  int e0 = (blockIdx.x & 3) * 16;
  int tid = threadIdx.x;
  int el = tid >> 4, g = tid & 15;

  float S0 = 0.f, S1 = 0.f, S2 = 0.f, S3 = 0.f;

  // prologue: stage chunk 0
  {
    Pref p = stage_load(qkv, alphaF, betaF, b, h, e0, 0, tid);
    stage_write(sm, p, tid);
  }
  __syncthreads();

  unsigned short* yb = y + (size_t)(b * SEQ) * 1024 + h * 64 + e0 + el;

  for (int c = 0; c < SEQ / TCH; ++c) {
    Pref p;
    if (c + 1 < SEQ / TCH)
      p = stage_load(qkv, alphaF, betaF, b, h, e0, (c + 1) * TCH, tid);

    const float* bb = sm + (c & 1) * BUFSZ;
#pragma unroll 4
    for (int t = 0; t < TCH; ++t) {
      float4 kk = *(const float4*)&bb[LKOF + t * 64 + g * 4];
      float4 qq = *(const float4*)&bb[LQOF + t * 64 + g * 4];
      float ve = bb[LVOF + t * 16 + el];
      float at = bb[LAOF + t], bt = bb[LBOF + t];
      float pred = S0 * kk.x + S1 * kk.y + S2 * kk.z + S3 * kk.w;
      float qs   = S0 * qq.x + S1 * qq.y + S2 * qq.z + S3 * qq.w;
      float kq   = kk.x * qq.x + kk.y * qq.y + kk.z * qq.z + kk.w * qq.w;
#pragma unroll
      for (int m = 1; m < 16; m <<= 1) {
        pred += __shfl_xor(pred, m);
        qs   += __shfl_xor(qs, m);
        kq   += __shfl_xor(kq, m);
      }
      float err = ve - pred;
      float be = bt * err;
      S0 = at * S0 + be * kk.x;
      S1 = at * S1 + be * kk.y;
      S2 = at * S2 + be * kk.z;
      S3 = at * S3 + be * kk.w;
      if (g == 0)
        yb[(size_t)(c * TCH + t) * 1024] = f2bf(at * qs + be * kq);
    }
    if (c + 1 < SEQ / TCH) {
      stage_write(sm + ((c + 1) & 1) * BUFSZ, p, tid);
      __syncthreads();
    }
  }
}

// ---------------------------------------------------------------- rmsnorm*gate
__global__ __launch_bounds__(256) void rmsgate_k(const unsigned short* __restrict__ y,
                                                 const unsigned short* __restrict__ gl,
                                                 const float* __restrict__ gnorm,
                                                 unsigned short* __restrict__ z) {
  __shared__ float red[4];
  int row = blockIdx.x, tid = threadIdx.x;
  size_t base = (size_t)row * 1024 + tid * 4;
  uint2 yv = *(const uint2*)&y[base];
  float f0 = bf2f((unsigned short)(yv.x & 0xffff)), f1 = bf2f((unsigned short)(yv.x >> 16));
  float f2 = bf2f((unsigned short)(yv.y & 0xffff)), f3 = bf2f((unsigned short)(yv.y >> 16));
  float ss = f0 * f0 + f1 * f1 + f2 * f2 + f3 * f3;
#pragma unroll
  for (int s = 1; s < 64; s <<= 1) ss += __shfl_xor(ss, s);
  if ((tid & 63) == 0) red[tid >> 6] = ss;
  __syncthreads();
  ss = red[0] + red[1] + red[2] + red[3];
  float rms = rsqrtf(ss * (1.0f / 1024.0f) + 1e-5f);
  uint2 gv = *(const uint2*)&gl[base];
  float4 gn = *(const float4*)&gnorm[tid * 4];
  float g[4] = {bf2f((unsigned short)(gv.x & 0xffff)), bf2f((unsigned short)(gv.x >> 16)),
                bf2f((unsigned short)(gv.y & 0xffff)), bf2f((unsigned short)(gv.y >> 16))};
  float gnv[4] = {gn.x, gn.y, gn.z, gn.w};
  float fv[4] = {f0, f1, f2, f3};
  unsigned short o[4];
#pragma unroll
  for (int jj = 0; jj < 4; jj++) {
    float gate = g[jj] / (1.f + expf(-g[jj]));  // silu
    o[jj] = f2bf(fv[jj] * rms * gnv[jj] * gate);
  }
  uint2 ov;
  ov.x = (unsigned int)o[0] | ((unsigned int)o[1] << 16);
  ov.y = (unsigned int)o[2] | ((unsigned int)o[3] << 16);
  *(uint2*)&z[base] = ov;
}

// ---------------------------------------------------------------- launch
extern "C" void kernel_launch(void* const* d_in, const int* in_sizes, int n_in,
                              void* d_out, int out_size, void* d_ws, size_t ws_size,
                              hipStream_t stream) {
  const float* x     = (const float*)d_in[0];
  const float* Wq    = (const float*)d_in[1];
  const float* Wk    = (const float*)d_in[2];
  const float* Wv    = (const float*)d_in[3];
  const float* Wa    = (const float*)d_in[4];
  const float* ba    = (const float*)d_in[5];
  const float* Wb    = (const float*)d_in[6];
  const float* bb    = (const float*)d_in[7];
  const float* Wg    = (const float*)d_in[8];
  const float* Wo    = (const float*)d_in[9];
  const float* gnorm = (const float*)d_in[10];
  float* out = (float*)d_out;

  unsigned short* xbf    = (unsigned short*)d_ws;                 // 8192*1024
  unsigned short* Bt_qkv = xbf + (size_t)NTOK * 1024;             // 3072*1024
  unsigned short* Bt_g   = Bt_qkv + (size_t)3072 * 1024;          // 1024*1024
  unsigned short* Bt_o   = Bt_g + (size_t)1024 * 1024;            // 1024*1024
  unsigned short* qkv    = Bt_o + (size_t)1024 * 1024;            // 8192*3072
  unsigned short* gatelin= qkv + (size_t)NTOK * 3072;             // 8192*1024
  unsigned short* ybuf   = gatelin + (size_t)NTOK * 1024;         // 8192*1024
  float* Wab             = (float*)(ybuf + (size_t)NTOK * 1024);  // 1024*32
  float* alphaF          = Wab + 1024 * 32;                       // 8192*16
  float* betaF           = alphaF + (size_t)NTOK * 16;            // 8192*16
  unsigned short* zbuf   = xbf;  // alias: xbf dead after gate GEMM

  castx_k<<<NTOK * 1024 / 4 / 256, 256, 0, stream>>>(x, xbf, NTOK * 1024 / 4);
  dim3 tb(32, 8);
  transpose_k<<<dim3(32, 32), tb, 0, stream>>>(Wq, Bt_qkv, 1024, 1024);
  transpose_k<<<dim3(32, 32), tb, 0, stream>>>(Wk, Bt_qkv + (size_t)1024 * 1024, 1024, 1024);
  transpose_k<<<dim3(32, 32), tb, 0, stream>>>(Wv, Bt_qkv + (size_t)2048 * 1024, 1024, 1024);
  transpose_k<<<dim3(32, 32), tb, 0, stream>>>(Wg, Bt_g, 1024, 1024);
  transpose_k<<<dim3(32, 32), tb, 0, stream>>>(Wo, Bt_o, 1024, 1024);
  build_wab<<<128, 256, 0, stream>>>(Wa, Wb, Wab);

  gemm_bt<false><<<(NTOK / 128) * (3072 / 128), 256, 0, stream>>>(xbf, Bt_qkv, qkv, NTOK, 3072, 1024);
  ab_kernel<<<NTOK / 8, 256, 0, stream>>>(x, Wab, ba, bb, alphaF, betaF);
  l2norm_k<<<65536, 256, 0, stream>>>(qkv);
  gemm_bt<false><<<(NTOK / 128) * (1024 / 128), 256, 0, stream>>>(xbf, Bt_g, gatelin, NTOK, 1024, 1024);
  scan_k<<<256, 256, 0, stream>>>(qkv, alphaF, betaF, ybuf);
  rmsgate_k<<<NTOK, 256, 0, stream>>>(ybuf, gatelin, gnorm, zbuf);
  gemm_bt<true><<<(NTOK / 128) * (1024 / 128), 256, 0, stream>>>(zbuf, Bt_o, out, NTOK, 1024, 1024);
}

// Round 4
// 885.419 us; speedup vs baseline: 2.6855x; 1.0216x over previous
//
#include <hip/hip_runtime.h>
#include <hip/hip_bf16.h>
#include <math.h>

typedef __attribute__((ext_vector_type(8))) short bf16x8s;
typedef __attribute__((ext_vector_type(4))) float f32x4;

#define SEQ 2048
#define NTOK 8192

static __device__ __forceinline__ float bf2f(unsigned short u) {
  union { unsigned int i; float f; } c; c.i = ((unsigned int)u) << 16; return c.f;
}
static __device__ __forceinline__ unsigned short f2bf(float f) {
  union { float f; unsigned int i; } c; c.f = f;
  unsigned int x = c.i;
  return (unsigned short)((x + 0x7FFFu + ((x >> 16) & 1u)) >> 16);
}

// ---------------------------------------------------------------- x cast fp32 -> bf16
__global__ __launch_bounds__(256) void castx_k(const float* __restrict__ in,
                                               unsigned short* __restrict__ out, int n4) {
  int i = blockIdx.x * 256 + threadIdx.x;
  if (i >= n4) return;
  float4 v = ((const float4*)in)[i];
  ushort4 o;
  o.x = f2bf(v.x); o.y = f2bf(v.y); o.z = f2bf(v.z); o.w = f2bf(v.w);
  ((ushort4*)out)[i] = o;
}

// ---------------------------------------------------------------- transpose fp32 -> bf16
__global__ void transpose_k(const float* __restrict__ in,
                            unsigned short* __restrict__ out, int R, int C) {
  __shared__ unsigned short tile[32][33];
  int c0 = blockIdx.x * 32, r0 = blockIdx.y * 32;
  int tx = threadIdx.x, ty = threadIdx.y;
  for (int i = ty; i < 32; i += 8)
    tile[i][tx] = f2bf(in[(size_t)(r0 + i) * C + c0 + tx]);
  __syncthreads();
  for (int i = ty; i < 32; i += 8)
    out[(size_t)(c0 + i) * R + r0 + tx] = tile[tx][i];
}

// ---------------------------------------------------------------- Wab concat (fp32)
__global__ void build_wab(const float* __restrict__ Wa,
                          const float* __restrict__ Wb,
                          float* __restrict__ Wab) {
  int i = blockIdx.x * 256 + threadIdx.x;  // 1024*32
  int k = i >> 5, j = i & 31;
  Wab[i] = (j < 16) ? Wa[k * 16 + j] : Wb[k * 16 + (j - 16)];
}

// ---------------------------------------------------------------- MFMA GEMM (m97 pattern)
// C[M,N] = A[M,K] * Bt[N,K]^T   (bf16 in, fp32 accum, bf16 or fp32 out)
// 128x128 tile, BK=32, 256 threads; global_load_lds width=16 staging into
// unpadded [128][32] LDS tiles (lane*16B == row*64B+col8*16B mapping).
template<bool F32OUT>
__global__ __launch_bounds__(256) void gemm_bt(const unsigned short* __restrict__ A,
                                               const unsigned short* __restrict__ Bt,
                                               void* __restrict__ Cv,
                                               int M, int N, int K) {
  __shared__ __align__(16) unsigned short As[128 * 32];
  __shared__ __align__(16) unsigned short Bs[128 * 32];
  int tiles_n = N >> 7;
  int tm = blockIdx.x / tiles_n, tn = blockIdx.x % tiles_n;
  int m0 = tm << 7, n0 = tn << 7;
  int tid = threadIdx.x;
  int wave = tid >> 6, lane = tid & 63;
  int wm = wave >> 1, wn = wave & 1;
  int r = lane & 15, qd = lane >> 4;
  int lr = lane >> 2, lc = lane & 3;  // staging: row-in-group, col8

  f32x4 acc[4][4];
#pragma unroll
  for (int mi = 0; mi < 4; mi++)
#pragma unroll
    for (int ni = 0; ni < 4; ni++) acc[mi][ni] = (f32x4){0.f, 0.f, 0.f, 0.f};

  for (int k0 = 0; k0 < K; k0 += 32) {
#pragma unroll
    for (int gi = 0; gi < 2; ++gi) {
      int g = wave + gi * 4;          // 16-row group 0..7
      int row = g * 16 + lr;
      const unsigned short* ga = A + (size_t)(m0 + row) * K + k0 + lc * 8;
      const unsigned short* gb = Bt + (size_t)(n0 + row) * K + k0 + lc * 8;
      __builtin_amdgcn_global_load_lds(
          (const __attribute__((address_space(1))) unsigned int*)ga,
          (__attribute__((address_space(3))) unsigned int*)(As + g * 512 + lane * 8),
          16, 0, 0);
      __builtin_amdgcn_global_load_lds(
          (const __attribute__((address_space(1))) unsigned int*)gb,
          (__attribute__((address_space(3))) unsigned int*)(Bs + g * 512 + lane * 8),
          16, 0, 0);
    }
    __syncthreads();
    bf16x8s af[4], bfr[4];
#pragma unroll
    for (int mi = 0; mi < 4; mi++)
      af[mi] = *(const bf16x8s*)&As[(wm * 64 + mi * 16 + r) * 32 + qd * 8];
#pragma unroll
    for (int ni = 0; ni < 4; ni++)
      bfr[ni] = *(const bf16x8s*)&Bs[(wn * 64 + ni * 16 + r) * 32 + qd * 8];
#pragma unroll
    for (int mi = 0; mi < 4; mi++)
#pragma unroll
      for (int ni = 0; ni < 4; ni++)
        acc[mi][ni] = __builtin_amdgcn_mfma_f32_16x16x32_bf16(af[mi], bfr[ni], acc[mi][ni], 0, 0, 0);
    __syncthreads();
  }
#pragma unroll
  for (int mi = 0; mi < 4; mi++)
#pragma unroll
    for (int ni = 0; ni < 4; ni++)
#pragma unroll
      for (int reg = 0; reg < 4; reg++) {
        int m = m0 + wm * 64 + mi * 16 + qd * 4 + reg;
        int n = n0 + wn * 64 + ni * 16 + r;
        if (F32OUT) ((float*)Cv)[(size_t)m * N + n] = acc[mi][ni][reg];
        else ((unsigned short*)Cv)[(size_t)m * N + n] = f2bf(acc[mi][ni][reg]);
      }
}

// ---------------------------------------------------------------- alpha/beta (pure fp32)
__global__ __launch_bounds__(256) void ab_kernel(const float* __restrict__ x,
                                                 const float* __restrict__ Wab,
                                                 const float* __restrict__ ba,
                                                 const float* __restrict__ bb,
                                                 float* __restrict__ alphaF,
                                                 float* __restrict__ betaF) {
  __shared__ __align__(16) float xs[8 * 1024];  // 32 KB
  int tid = threadIdx.x;
  int m0 = blockIdx.x * 8;
  const float* xg = x + (size_t)m0 * 1024;
  for (int i = tid; i < 2048; i += 256)
    *(float4*)&xs[i * 4] = *(const float4*)&xg[i * 4];
  __syncthreads();
  int mi = tid >> 5, j = tid & 31;
  float acc = 0.f;
#pragma unroll 8
  for (int k = 0; k < 1024; ++k)
    acc += xs[mi * 1024 + k] * Wab[k * 32 + j];
  float bias = (j < 16) ? ba[j] : bb[j - 16];
  float s = 1.f / (1.f + expf(-(acc + bias)));
  int m = m0 + mi;
  if (j < 16) alphaF[m * 16 + j] = s;
  else        betaF[m * 16 + (j - 16)] = s;
}

// ---------------------------------------------------------------- L2 norm q,k (in-place bf16)
__global__ __launch_bounds__(256) void l2norm_k(unsigned short* __restrict__ qkv) {
  int id = blockIdx.x * 4 + (threadIdx.x >> 6);
  int lane = threadIdx.x & 63;
  int which = id >> 17;
  int mh = id & 131071;
  int m = mh >> 4, h = mh & 15;
  size_t off = (size_t)m * 3072 + (size_t)which * 1024 + h * 64 + lane;
  float v = bf2f(qkv[off]);
  float ss = v * v;
#pragma unroll
  for (int s = 1; s < 64; s <<= 1) ss += __shfl_xor(ss, s);
  float scale = 1.0f / fmaxf(sqrtf(ss), 1e-12f);
  qkv[off] = f2bf(v * scale);
}

// ---------------------------------------------------------------- scan
// Column decomposition: S[:,e] independent per e. Grid 256 = (b*16+h)*4+eq.
// Block = 64 threads (ONE wave). lane = el*4+g: el = column (e = eq*16+el),
// g = d-quarter (16 d's). Quad reduction via DPP quad_perm (VALU, no DS).
// kq precomputed per chunk at staging (off critical path).
#define TC 32
#define NCH (SEQ / TC)
#define LK 0
#define LQ 2048
#define LV 4096
#define LA 4608
#define LB 4640
#define LKQ 4672
#define SBUF 4704

static __device__ __forceinline__ float quad_add(float x) {
  union { float f; int i; } c, d;
  c.f = x;
  d.i = __builtin_amdgcn_update_dpp(0, c.i, 0xB1, 0xF, 0xF, true);  // quad_perm [1,0,3,2]
  float s1 = x + d.f;
  c.f = s1;
  d.i = __builtin_amdgcn_update_dpp(0, c.i, 0x4E, 0xF, 0xF, true);  // quad_perm [2,3,0,1]
  return s1 + d.f;
}

static __device__ __forceinline__ void unpack8(uint4 v, float* f) {
  f[0] = bf2f((unsigned short)(v.x & 0xffff)); f[1] = bf2f((unsigned short)(v.x >> 16));
  f[2] = bf2f((unsigned short)(v.y & 0xffff)); f[3] = bf2f((unsigned short)(v.y >> 16));
  f[4] = bf2f((unsigned short)(v.z & 0xffff)); f[5] = bf2f((unsigned short)(v.z >> 16));
  f[6] = bf2f((unsigned short)(v.w & 0xffff)); f[7] = bf2f((unsigned short)(v.w >> 16));
}

struct Pref { uint4 k8[4], q8[4], v8; float ab; };

static __device__ __forceinline__ Pref scan_load(const unsigned short* __restrict__ qkv,
                                                 const float* __restrict__ alphaF,
                                                 const float* __restrict__ betaF,
                                                 int b, int h, int eq, int t0, int tid) {
  Pref p;
  const unsigned short* base = qkv + (size_t)(b * SEQ + t0) * 3072 + h * 64;
#pragma unroll
  for (int j = 0; j < 4; ++j) {
    int c = tid + 64 * j;  // c = t*8 + seg
    int t = c >> 3, seg = c & 7;
    p.q8[j] = *(const uint4*)(base + (size_t)t * 3072 + seg * 8);
    p.k8[j] = *(const uint4*)(base + (size_t)t * 3072 + 1024 + seg * 8);
  }
  {
    int t = tid >> 1, half = tid & 1;
    p.v8 = *(const uint4*)(base + (size_t)t * 3072 + 2048 + eq * 16 + half * 8);
  }
  if (tid < 32) p.ab = alphaF[(size_t)(b * SEQ + t0 + tid) * 16 + h];
  else          p.ab = betaF[(size_t)(b * SEQ + t0 + (tid - 32)) * 16 + h];
  return p;
}

static __device__ __forceinline__ void scan_store(float* __restrict__ buf, const Pref& p, int tid) {
#pragma unroll
  for (int j = 0; j < 4; ++j) {
    int c = tid + 64 * j;
    int t = c >> 3, seg = c & 7;
    float kf[8], qf[8];
    unpack8(p.k8[j], kf);
    unpack8(p.q8[j], qf);
    *(float4*)&buf[LK + t * 64 + seg * 8]     = (float4){kf[0], kf[1], kf[2], kf[3]};
    *(float4*)&buf[LK + t * 64 + seg * 8 + 4] = (float4){kf[4], kf[5], kf[6], kf[7]};
    *(float4*)&buf[LQ + t * 64 + seg * 8]     = (float4){qf[0], qf[1], qf[2], qf[3]};
    *(float4*)&buf[LQ + t * 64 + seg * 8 + 4] = (float4){qf[4], qf[5], qf[6], qf[7]};
    float s = kf[0]*qf[0] + kf[1]*qf[1] + kf[2]*qf[2] + kf[3]*qf[3]
            + kf[4]*qf[4] + kf[5]*qf[5] + kf[6]*qf[6] + kf[7]*qf[7];
    s += __shfl_xor(s, 1); s += __shfl_xor(s, 2); s += __shfl_xor(s, 4);
    if (seg == 0) buf[LKQ + t] = s;  // kq_t = k_t . q_t
  }
  {
    int t = tid >> 1, half = tid & 1;
    float vf[8];
    unpack8(p.v8, vf);
    *(float4*)&buf[LV + t * 16 + half * 8]     = (float4){vf[0], vf[1], vf[2], vf[3]};
    *(float4*)&buf[LV + t * 16 + half * 8 + 4] = (float4){vf[4], vf[5], vf[6], vf[7]};
  }
  if (tid < 32) buf[LA + tid] = p.ab;
  else          buf[LB + tid - 32] = p.ab;
}

__global__ __launch_bounds__(64) void scan_k(const unsigned short* __restrict__ qkv,
                                             const float* __restrict__ alphaF,
                                             const float* __restrict__ betaF,
                                             unsigned short* __restrict__ y) {
  __shared__ float sm[2 * SBUF];  // 36.75 KB
  int bh = blockIdx.x >> 2, eq = blockIdx.x & 3;
  int b = bh >> 4, h = bh & 15;
  int tid = threadIdx.x;
  int el = tid >> 2, g = tid & 3;

  float S[16];
#pragma unroll
  for (int j = 0; j < 16; j++) S[j] = 0.f;

  Pref p = scan_load(qkv, alphaF, betaF, b, h, eq, 0, tid);
  scan_store(sm, p, tid);
  __syncthreads();

  unsigned short* yb = y + (size_t)(b * SEQ) * 1024 + h * 64 + eq * 16 + el;

  for (int c = 0; c < NCH; ++c) {
    if (c + 1 < NCH)
      p = scan_load(qkv, alphaF, betaF, b, h, eq, (c + 1) * TC, tid);

    const float* bb = sm + (c & 1) * SBUF;
#pragma unroll 2
    for (int t = 0; t < TC; ++t) {
      const float* kr = &bb[LK + t * 64 + g * 16];
      const float* qr = &bb[LQ + t * 64 + g * 16];
      float4 k0 = *(const float4*)kr,        k1 = *(const float4*)(kr + 4);
      float4 k2 = *(const float4*)(kr + 8),  k3 = *(const float4*)(kr + 12);
      float4 q0 = *(const float4*)qr,        q1 = *(const float4*)(qr + 4);
      float4 q2 = *(const float4*)(qr + 8),  q3 = *(const float4*)(qr + 12);
      float ve = bb[LV + t * 16 + el];
      float at = bb[LA + t], bt = bb[LB + t], kq = bb[LKQ + t];
      float p0 = S[0]*k0.x + S[1]*k0.y + S[2]*k0.z + S[3]*k0.w;
      float p1 = S[4]*k1.x + S[5]*k1.y + S[6]*k1.z + S[7]*k1.w;
      float p2 = S[8]*k2.x + S[9]*k2.y + S[10]*k2.z + S[11]*k2.w;
      float p3 = S[12]*k3.x + S[13]*k3.y + S[14]*k3.z + S[15]*k3.w;
      float pr = (p0 + p1) + (p2 + p3);
      float u0 = S[0]*q0.x + S[1]*q0.y + S[2]*q0.z + S[3]*q0.w;
      float u1 = S[4]*q1.x + S[5]*q1.y + S[6]*q1.z + S[7]*q1.w;
      float u2 = S[8]*q2.x + S[9]*q2.y + S[10]*q2.z + S[11]*q2.w;
      float u3 = S[12]*q3.x + S[13]*q3.y + S[14]*q3.z + S[15]*q3.w;
      float qs = (u0 + u1) + (u2 + u3);
      pr = quad_add(pr);
      qs = quad_add(qs);
      float be = bt * (ve - pr);
      S[0] = at*S[0] + be*k0.x;  S[1] = at*S[1] + be*k0.y;
      S[2] = at*S[2] + be*k0.z;  S[3] = at*S[3] + be*k0.w;
      S[4] = at*S[4] + be*k1.x;  S[5] = at*S[5] + be*k1.y;
      S[6] = at*S[6] + be*k1.z;  S[7] = at*S[7] + be*k1.w;
      S[8] = at*S[8] + be*k2.x;  S[9] = at*S[9] + be*k2.y;
      S[10] = at*S[10] + be*k2.z; S[11] = at*S[11] + be*k2.w;
      S[12] = at*S[12] + be*k3.x; S[13] = at*S[13] + be*k3.y;
      S[14] = at*S[14] + be*k3.z; S[15] = at*S[15] + be*k3.w;
      if (g == 0)
        yb[(size_t)(c * TC + t) * 1024] = f2bf(at * qs + be * kq);
    }
    if (c + 1 < NCH) {
      scan_store(sm + ((c + 1) & 1) * SBUF, p, tid);
      __syncthreads();
    }
  }
}

// ---------------------------------------------------------------- rmsnorm*gate
__global__ __launch_bounds__(256) void rmsgate_k(const unsigned short* __restrict__ y,
                                                 const unsigned short* __restrict__ gl,
                                                 const float* __restrict__ gnorm,
                                                 unsigned short* __restrict__ z) {
  __shared__ float red[4];
  int row = blockIdx.x, tid = threadIdx.x;
  size_t base = (size_t)row * 1024 + tid * 4;
  uint2 yv = *(const uint2*)&y[base];
  float f0 = bf2f((unsigned short)(yv.x & 0xffff)), f1 = bf2f((unsigned short)(yv.x >> 16));
  float f2 = bf2f((unsigned short)(yv.y & 0xffff)), f3 = bf2f((unsigned short)(yv.y >> 16));
  float ss = f0 * f0 + f1 * f1 + f2 * f2 + f3 * f3;
#pragma unroll
  for (int s = 1; s < 64; s <<= 1) ss += __shfl_xor(ss, s);
  if ((tid & 63) == 0) red[tid >> 6] = ss;
  __syncthreads();
  ss = red[0] + red[1] + red[2] + red[3];
  float rms = rsqrtf(ss * (1.0f / 1024.0f) + 1e-5f);
  uint2 gv = *(const uint2*)&gl[base];
  float4 gn = *(const float4*)&gnorm[tid * 4];
  float g[4] = {bf2f((unsigned short)(gv.x & 0xffff)), bf2f((unsigned short)(gv.x >> 16)),
                bf2f((unsigned short)(gv.y & 0xffff)), bf2f((unsigned short)(gv.y >> 16))};
  float gnv[4] = {gn.x, gn.y, gn.z, gn.w};
  float fv[4] = {f0, f1, f2, f3};
  unsigned short o[4];
#pragma unroll
  for (int jj = 0; jj < 4; jj++) {
    float gate = g[jj] / (1.f + expf(-g[jj]));  // silu
    o[jj] = f2bf(fv[jj] * rms * gnv[jj] * gate);
  }
  uint2 ov;
  ov.x = (unsigned int)o[0] | ((unsigned int)o[1] << 16);
  ov.y = (unsigned int)o[2] | ((unsigned int)o[3] << 16);
  *(uint2*)&z[base] = ov;
}

// ---------------------------------------------------------------- launch
extern "C" void kernel_launch(void* const* d_in, const int* in_sizes, int n_in,
                              void* d_out, int out_size, void* d_ws, size_t ws_size,
                              hipStream_t stream) {
  const float* x     = (const float*)d_in[0];
  const float* Wq    = (const float*)d_in[1];
  const float* Wk    = (const float*)d_in[2];
  const float* Wv    = (const float*)d_in[3];
  const float* Wa    = (const float*)d_in[4];
  const float* ba    = (const float*)d_in[5];
  const float* Wb    = (const float*)d_in[6];
  const float* bb    = (const float*)d_in[7];
  const float* Wg    = (const float*)d_in[8];
  const float* Wo    = (const float*)d_in[9];
  const float* gnorm = (const float*)d_in[10];
  float* out = (float*)d_out;

  unsigned short* xbf    = (unsigned short*)d_ws;                 // 8192*1024
  unsigned short* Bt_qkv = xbf + (size_t)NTOK * 1024;             // 3072*1024
  unsigned short* Bt_g   = Bt_qkv + (size_t)3072 * 1024;          // 1024*1024
  unsigned short* Bt_o   = Bt_g + (size_t)1024 * 1024;            // 1024*1024
  unsigned short* qkv    = Bt_o + (size_t)1024 * 1024;            // 8192*3072
  unsigned short* gatelin= qkv + (size_t)NTOK * 3072;             // 8192*1024
  unsigned short* ybuf   = gatelin + (size_t)NTOK * 1024;         // 8192*1024
  float* Wab             = (float*)(ybuf + (size_t)NTOK * 1024);  // 1024*32
  float* alphaF          = Wab + 1024 * 32;                       // 8192*16
  float* betaF           = alphaF + (size_t)NTOK * 16;            // 8192*16
  unsigned short* zbuf   = xbf;  // alias: xbf dead after gate GEMM

  castx_k<<<NTOK * 1024 / 4 / 256, 256, 0, stream>>>(x, xbf, NTOK * 1024 / 4);
  dim3 tb(32, 8);
  transpose_k<<<dim3(32, 32), tb, 0, stream>>>(Wq, Bt_qkv, 1024, 1024);
  transpose_k<<<dim3(32, 32), tb, 0, stream>>>(Wk, Bt_qkv + (size_t)1024 * 1024, 1024, 1024);
  transpose_k<<<dim3(32, 32), tb, 0, stream>>>(Wv, Bt_qkv + (size_t)2048 * 1024, 1024, 1024);
  transpose_k<<<dim3(32, 32), tb, 0, stream>>>(Wg, Bt_g, 1024, 1024);
  transpose_k<<<dim3(32, 32), tb, 0, stream>>>(Wo, Bt_o, 1024, 1024);
  build_wab<<<128, 256, 0, stream>>>(Wa, Wb, Wab);

  gemm_bt<false><<<(NTOK / 128) * (3072 / 128), 256, 0, stream>>>(xbf, Bt_qkv, qkv, NTOK, 3072, 1024);
  ab_kernel<<<NTOK / 8, 256, 0, stream>>>(x, Wab, ba, bb, alphaF, betaF);
  l2norm_k<<<65536, 256, 0, stream>>>(qkv);
  gemm_bt<false><<<(NTOK / 128) * (1024 / 128), 256, 0, stream>>>(xbf, Bt_g, gatelin, NTOK, 1024, 1024);
  scan_k<<<256, 64, 0, stream>>>(qkv, alphaF, betaF, ybuf);
  rmsgate_k<<<NTOK, 256, 0, stream>>>(ybuf, gatelin, gnorm, zbuf);
  gemm_bt<true><<<(NTOK / 128) * (1024 / 128), 256, 0, stream>>>(zbuf, Bt_o, out, NTOK, 1024, 1024);
}

// Round 5
// 762.719 us; speedup vs baseline: 3.1175x; 1.1609x over previous
//
#include <hip/hip_runtime.h>
#include <hip/hip_bf16.h>
#include <math.h>

typedef __attribute__((ext_vector_type(8))) short bf16x8s;
typedef __attribute__((ext_vector_type(4))) float f32x4;

#define SEQ 2048
#define NTOK 8192
#define NQKV 3200   // 3072 qkv + 32 ab + 96 zero-pad

static __device__ __forceinline__ float bf2f(unsigned short u) {
  union { unsigned int i; float f; } c; c.i = ((unsigned int)u) << 16; return c.f;
}
static __device__ __forceinline__ unsigned short f2bf(float f) {
  union { float f; unsigned int i; } c; c.f = f;
  unsigned int x = c.i;
  return (unsigned short)((x + 0x7FFFu + ((x >> 16) & 1u)) >> 16);
}

// ---------------------------------------------------------------- x cast fp32 -> bf16
__global__ __launch_bounds__(256) void castx_k(const float* __restrict__ in,
                                               unsigned short* __restrict__ out, int n4) {
  int i = blockIdx.x * 256 + threadIdx.x;
  if (i >= n4) return;
  float4 v = ((const float4*)in)[i];
  ushort4 o;
  o.x = f2bf(v.x); o.y = f2bf(v.y); o.z = f2bf(v.z); o.w = f2bf(v.w);
  ((ushort4*)out)[i] = o;
}

// ---------------------------------------------------------------- transpose fp32 -> bf16
__global__ void transpose_k(const float* __restrict__ in,
                            unsigned short* __restrict__ out, int R, int C) {
  __shared__ unsigned short tile[32][33];
  int c0 = blockIdx.x * 32, r0 = blockIdx.y * 32;
  int tx = threadIdx.x, ty = threadIdx.y;
  for (int i = ty; i < 32; i += 8)
    tile[i][tx] = f2bf(in[(size_t)(r0 + i) * C + c0 + tx]);
  __syncthreads();
  for (int i = ty; i < 32; i += 8)
    out[(size_t)(c0 + i) * R + r0 + tx] = tile[tx][i];
}

// ---------------------------------------------------------------- Wab^T rows (bf16) + zero pad
__global__ void build_wabT(const float* __restrict__ Wa,
                           const float* __restrict__ Wb,
                           unsigned short* __restrict__ rows) {  // rows = Bt + 3072*1024
  int i = blockIdx.x * 256 + threadIdx.x;  // 128 * 1024
  int j = i >> 10, k = i & 1023;
  float v = 0.f;
  if (j < 16) v = Wa[k * 16 + j];
  else if (j < 32) v = Wb[k * 16 + (j - 16)];
  rows[(size_t)j * 1024 + k] = f2bf(v);
}

// ---------------------------------------------------------------- MFMA GEMM (m97 staging)
// C[M,N] = A[M,K] * Bt[N,K]^T. MODE 0: bf16 out; 1: f32 out;
// 2: fused qkv (bf16, stride 3072) + alpha/beta sigmoid (cols 3072..3103).
template<int MODE>
__global__ __launch_bounds__(256) void gemm_bt(const unsigned short* __restrict__ A,
                                               const unsigned short* __restrict__ Bt,
                                               void* __restrict__ Cv,
                                               int M, int N, int K,
                                               const float* __restrict__ ba,
                                               const float* __restrict__ bbp,
                                               float* __restrict__ alphaF,
                                               float* __restrict__ betaF) {
  __shared__ __align__(16) unsigned short As[128 * 32];
  __shared__ __align__(16) unsigned short Bs[128 * 32];
  int tiles_n = N >> 7;
  int tm = blockIdx.x / tiles_n, tn = blockIdx.x % tiles_n;
  int m0 = tm << 7, n0 = tn << 7;
  int tid = threadIdx.x;
  int wave = tid >> 6, lane = tid & 63;
  int wm = wave >> 1, wn = wave & 1;
  int r = lane & 15, qd = lane >> 4;
  int lr = lane >> 2, lc = lane & 3;

  f32x4 acc[4][4];
#pragma unroll
  for (int mi = 0; mi < 4; mi++)
#pragma unroll
    for (int ni = 0; ni < 4; ni++) acc[mi][ni] = (f32x4){0.f, 0.f, 0.f, 0.f};

  for (int k0 = 0; k0 < K; k0 += 32) {
#pragma unroll
    for (int gi = 0; gi < 2; ++gi) {
      int g = wave + gi * 4;
      int row = g * 16 + lr;
      const unsigned short* ga = A + (size_t)(m0 + row) * K + k0 + lc * 8;
      const unsigned short* gb = Bt + (size_t)(n0 + row) * K + k0 + lc * 8;
      __builtin_amdgcn_global_load_lds(
          (const __attribute__((address_space(1))) unsigned int*)ga,
          (__attribute__((address_space(3))) unsigned int*)(As + g * 512 + lane * 8),
          16, 0, 0);
      __builtin_amdgcn_global_load_lds(
          (const __attribute__((address_space(1))) unsigned int*)gb,
          (__attribute__((address_space(3))) unsigned int*)(Bs + g * 512 + lane * 8),
          16, 0, 0);
    }
    __syncthreads();
    bf16x8s af[4], bfr[4];
#pragma unroll
    for (int mi = 0; mi < 4; mi++)
      af[mi] = *(const bf16x8s*)&As[(wm * 64 + mi * 16 + r) * 32 + qd * 8];
#pragma unroll
    for (int ni = 0; ni < 4; ni++)
      bfr[ni] = *(const bf16x8s*)&Bs[(wn * 64 + ni * 16 + r) * 32 + qd * 8];
#pragma unroll
    for (int mi = 0; mi < 4; mi++)
#pragma unroll
      for (int ni = 0; ni < 4; ni++)
        acc[mi][ni] = __builtin_amdgcn_mfma_f32_16x16x32_bf16(af[mi], bfr[ni], acc[mi][ni], 0, 0, 0);
    __syncthreads();
  }
#pragma unroll
  for (int mi = 0; mi < 4; mi++)
#pragma unroll
    for (int ni = 0; ni < 4; ni++)
#pragma unroll
      for (int reg = 0; reg < 4; reg++) {
        int m = m0 + wm * 64 + mi * 16 + qd * 4 + reg;
        int n = n0 + wn * 64 + ni * 16 + r;
        float a = acc[mi][ni][reg];
        if (MODE == 0) ((unsigned short*)Cv)[(size_t)m * N + n] = f2bf(a);
        else if (MODE == 1) ((float*)Cv)[(size_t)m * N + n] = a;
        else {
          if (n < 3072) ((unsigned short*)Cv)[(size_t)m * 3072 + n] = f2bf(a);
          else if (n < 3104) {
            int j = n - 3072;
            float bias = (j < 16) ? ba[j] : bbp[j - 16];
            float s = 1.f / (1.f + expf(-(a + bias)));
            if (j < 16) alphaF[(size_t)m * 16 + j] = s;
            else        betaF[(size_t)m * 16 + (j - 16)] = s;
          }
        }
      }
}

// ---------------------------------------------------------------- L2 norm q,k (in-place bf16)
__global__ __launch_bounds__(256) void l2norm_k(unsigned short* __restrict__ qkv) {
  int id = blockIdx.x * 4 + (threadIdx.x >> 6);
  int lane = threadIdx.x & 63;
  int which = id >> 17;
  int mh = id & 131071;
  int m = mh >> 4, h = mh & 15;
  size_t off = (size_t)m * 3072 + (size_t)which * 1024 + h * 64 + lane;
  float v = bf2f(qkv[off]);
  float ss = v * v;
#pragma unroll
  for (int s = 1; s < 64; s <<= 1) ss += __shfl_xor(ss, s);
  float scale = 1.0f / fmaxf(sqrtf(ss), 1e-12f);
  qkv[off] = f2bf(v * scale);
}

// ---------------------------------------------------------------- scan
// 512 blocks = (b*16+h)*8 + ec; block = 64 thr (ONE wave).
// lane = el*8+g: el = local e (e = ec*8+el), g = d-octet (8 d's).
// 8 fp32 S regs/lane. Reduction over g: 2 DPP quad ops + 1 ds_swizzle(xor4).
// Inner loop register-prefetches step t+1's LDS data (latency off the chain).
#define TC 32
#define NCH (SEQ / TC)
#define LK 0
#define LQ 2048
#define LV 4096
#define LA 4352
#define LB 4384
#define LKQ 4416
#define SBUF 4448

static __device__ __forceinline__ float quad_add(float x) {
  union { float f; int i; } c, d;
  c.f = x;
  d.i = __builtin_amdgcn_update_dpp(0, c.i, 0xB1, 0xF, 0xF, true);  // quad_perm [1,0,3,2]
  float s1 = x + d.f;
  c.f = s1;
  d.i = __builtin_amdgcn_update_dpp(0, c.i, 0x4E, 0xF, 0xF, true);  // quad_perm [2,3,0,1]
  return s1 + d.f;
}
static __device__ __forceinline__ float red8(float x) {
  float s = quad_add(x);
  union { float f; int i; } c, d;
  c.f = s;
  d.i = __builtin_amdgcn_ds_swizzle(c.i, 0x101F);  // lane ^= 4
  return s + d.f;
}

static __device__ __forceinline__ void unpack8(uint4 v, float* f) {
  f[0] = bf2f((unsigned short)(v.x & 0xffff)); f[1] = bf2f((unsigned short)(v.x >> 16));
  f[2] = bf2f((unsigned short)(v.y & 0xffff)); f[3] = bf2f((unsigned short)(v.y >> 16));
  f[4] = bf2f((unsigned short)(v.z & 0xffff)); f[5] = bf2f((unsigned short)(v.z >> 16));
  f[6] = bf2f((unsigned short)(v.w & 0xffff)); f[7] = bf2f((unsigned short)(v.w >> 16));
}

struct Pref { uint4 k8[4], q8[4], v8; float ab; };

static __device__ __forceinline__ Pref scan_load(const unsigned short* __restrict__ qkv,
                                                 const float* __restrict__ alphaF,
                                                 const float* __restrict__ betaF,
                                                 int b, int h, int ec, int t0, int tid) {
  Pref p; p.v8 = (uint4){0, 0, 0, 0};
  const unsigned short* base = qkv + (size_t)(b * SEQ + t0) * 3072 + h * 64;
#pragma unroll
  for (int j = 0; j < 4; ++j) {
    int idx = j * 64 + tid;          // t*8 + seg
    int t = idx >> 3, seg = idx & 7;
    p.q8[j] = *(const uint4*)(base + (size_t)t * 3072 + seg * 8);
    p.k8[j] = *(const uint4*)(base + (size_t)t * 3072 + 1024 + seg * 8);
  }
  if (tid < 32) {
    p.v8 = *(const uint4*)(base + (size_t)tid * 3072 + 2048 + ec * 8);
    p.ab = alphaF[(size_t)(b * SEQ + t0 + tid) * 16 + h];
  } else {
    p.ab = betaF[(size_t)(b * SEQ + t0 + (tid - 32)) * 16 + h];
  }
  return p;
}

static __device__ __forceinline__ void scan_store(float* __restrict__ buf, const Pref& p, int tid) {
#pragma unroll
  for (int j = 0; j < 4; ++j) {
    int idx = j * 64 + tid;
    int t = idx >> 3, seg = idx & 7;
    float kf[8], qf[8];
    unpack8(p.k8[j], kf);
    unpack8(p.q8[j], qf);
    *(float4*)&buf[LK + t * 64 + seg * 8]     = (float4){kf[0], kf[1], kf[2], kf[3]};
    *(float4*)&buf[LK + t * 64 + seg * 8 + 4] = (float4){kf[4], kf[5], kf[6], kf[7]};
    *(float4*)&buf[LQ + t * 64 + seg * 8]     = (float4){qf[0], qf[1], qf[2], qf[3]};
    *(float4*)&buf[LQ + t * 64 + seg * 8 + 4] = (float4){qf[4], qf[5], qf[6], qf[7]};
    float s = kf[0]*qf[0] + kf[1]*qf[1] + kf[2]*qf[2] + kf[3]*qf[3]
            + kf[4]*qf[4] + kf[5]*qf[5] + kf[6]*qf[6] + kf[7]*qf[7];
    s = red8(s);                     // reduce over seg (= tid&7)
    if ((tid & 7) == 0) buf[LKQ + t] = s;
  }
  if (tid < 32) {
    float vf[8];
    unpack8(p.v8, vf);
    *(float4*)&buf[LV + tid * 8]     = (float4){vf[0], vf[1], vf[2], vf[3]};
    *(float4*)&buf[LV + tid * 8 + 4] = (float4){vf[4], vf[5], vf[6], vf[7]};
    buf[LA + tid] = p.ab;
  } else {
    buf[LB + tid - 32] = p.ab;
  }
}

__global__ __launch_bounds__(64) void scan_k(const unsigned short* __restrict__ qkv,
                                             const float* __restrict__ alphaF,
                                             const float* __restrict__ betaF,
                                             unsigned short* __restrict__ y) {
  __shared__ float sm[2 * SBUF];  // 35.6 KB
  int bh = blockIdx.x >> 3, ec = blockIdx.x & 7;
  int b = bh >> 4, h = bh & 15;
  int tid = threadIdx.x;
  int el = tid >> 3, g = tid & 7;

  float S0 = 0.f, S1 = 0.f, S2 = 0.f, S3 = 0.f;
  float S4 = 0.f, S5 = 0.f, S6 = 0.f, S7 = 0.f;

  Pref p = scan_load(qkv, alphaF, betaF, b, h, ec, 0, tid);
  scan_store(sm, p, tid);
  __syncthreads();

  unsigned short* yb = y + (size_t)(b * SEQ) * 1024 + h * 64 + ec * 8 + el;

  for (int c = 0; c < NCH; ++c) {
    if (c + 1 < NCH)
      p = scan_load(qkv, alphaF, betaF, b, h, ec, (c + 1) * TC, tid);

    const float* bb = sm + (c & 1) * SBUF;
    // register-prefetch step 0
    float4 k0 = *(const float4*)&bb[LK + g * 8];
    float4 k1 = *(const float4*)&bb[LK + g * 8 + 4];
    float4 q0 = *(const float4*)&bb[LQ + g * 8];
    float4 q1 = *(const float4*)&bb[LQ + g * 8 + 4];
    float ve = bb[LV + el];
    float at = bb[LA], bt = bb[LB], kqv = bb[LKQ];
#pragma unroll 4
    for (int t = 0; t < TC; ++t) {
      int tn = (t + 1 < TC) ? t + 1 : t;
      float4 nk0 = *(const float4*)&bb[LK + tn * 64 + g * 8];
      float4 nk1 = *(const float4*)&bb[LK + tn * 64 + g * 8 + 4];
      float4 nq0 = *(const float4*)&bb[LQ + tn * 64 + g * 8];
      float4 nq1 = *(const float4*)&bb[LQ + tn * 64 + g * 8 + 4];
      float nve = bb[LV + tn * 8 + el];
      float nat = bb[LA + tn], nbt = bb[LB + tn], nkq = bb[LKQ + tn];

      float pr = ((S0*k0.x + S1*k0.y) + (S2*k0.z + S3*k0.w))
               + ((S4*k1.x + S5*k1.y) + (S6*k1.z + S7*k1.w));
      float qs = ((S0*q0.x + S1*q0.y) + (S2*q0.z + S3*q0.w))
               + ((S4*q1.x + S5*q1.y) + (S6*q1.z + S7*q1.w));
      pr = red8(pr);
      qs = red8(qs);
      float be = bt * (ve - pr);
      S0 = at*S0 + be*k0.x;  S1 = at*S1 + be*k0.y;
      S2 = at*S2 + be*k0.z;  S3 = at*S3 + be*k0.w;
      S4 = at*S4 + be*k1.x;  S5 = at*S5 + be*k1.y;
      S6 = at*S6 + be*k1.z;  S7 = at*S7 + be*k1.w;
      if (g == 0)
        yb[(size_t)(c * TC + t) * 1024] = f2bf(at * qs + be * kqv);

      k0 = nk0; k1 = nk1; q0 = nq0; q1 = nq1;
      ve = nve; at = nat; bt = nbt; kqv = nkq;
    }
    if (c + 1 < NCH) {
      scan_store(sm + ((c + 1) & 1) * SBUF, p, tid);
      __syncthreads();
    }
  }
}

// ---------------------------------------------------------------- rmsnorm*gate
__global__ __launch_bounds__(256) void rmsgate_k(const unsigned short* __restrict__ y,
                                                 const unsigned short* __restrict__ gl,
                                                 const float* __restrict__ gnorm,
                                                 unsigned short* __restrict__ z) {
  __shared__ float red[4];
  int row = blockIdx.x, tid = threadIdx.x;
  size_t base = (size_t)row * 1024 + tid * 4;
  uint2 yv = *(const uint2*)&y[base];
  float f0 = bf2f((unsigned short)(yv.x & 0xffff)), f1 = bf2f((unsigned short)(yv.x >> 16));
  float f2 = bf2f((unsigned short)(yv.y & 0xffff)), f3 = bf2f((unsigned short)(yv.y >> 16));
  float ss = f0 * f0 + f1 * f1 + f2 * f2 + f3 * f3;
#pragma unroll
  for (int s = 1; s < 64; s <<= 1) ss += __shfl_xor(ss, s);
  if ((tid & 63) == 0) red[tid >> 6] = ss;
  __syncthreads();
  ss = red[0] + red[1] + red[2] + red[3];
  float rms = rsqrtf(ss * (1.0f / 1024.0f) + 1e-5f);
  uint2 gv = *(const uint2*)&gl[base];
  float4 gn = *(const float4*)&gnorm[tid * 4];
  float g[4] = {bf2f((unsigned short)(gv.x & 0xffff)), bf2f((unsigned short)(gv.x >> 16)),
                bf2f((unsigned short)(gv.y & 0xffff)), bf2f((unsigned short)(gv.y >> 16))};
  float gnv[4] = {gn.x, gn.y, gn.z, gn.w};
  float fv[4] = {f0, f1, f2, f3};
  unsigned short o[4];
#pragma unroll
  for (int jj = 0; jj < 4; jj++) {
    float gate = g[jj] / (1.f + expf(-g[jj]));  // silu
    o[jj] = f2bf(fv[jj] * rms * gnv[jj] * gate);
  }
  uint2 ov;
  ov.x = (unsigned int)o[0] | ((unsigned int)o[1] << 16);
  ov.y = (unsigned int)o[2] | ((unsigned int)o[3] << 16);
  *(uint2*)&z[base] = ov;
}

// ---------------------------------------------------------------- launch
extern "C" void kernel_launch(void* const* d_in, const int* in_sizes, int n_in,
                              void* d_out, int out_size, void* d_ws, size_t ws_size,
                              hipStream_t stream) {
  const float* x     = (const float*)d_in[0];
  const float* Wq    = (const float*)d_in[1];
  const float* Wk    = (const float*)d_in[2];
  const float* Wv    = (const float*)d_in[3];
  const float* Wa    = (const float*)d_in[4];
  const float* ba    = (const float*)d_in[5];
  const float* Wb    = (const float*)d_in[6];
  const float* bb    = (const float*)d_in[7];
  const float* Wg    = (const float*)d_in[8];
  const float* Wo    = (const float*)d_in[9];
  const float* gnorm = (const float*)d_in[10];
  float* out = (float*)d_out;

  unsigned short* xbf    = (unsigned short*)d_ws;                 // 8192*1024
  unsigned short* Bt_qkv = xbf + (size_t)NTOK * 1024;             // 3200*1024
  unsigned short* Bt_g   = Bt_qkv + (size_t)NQKV * 1024;          // 1024*1024
  unsigned short* Bt_o   = Bt_g + (size_t)1024 * 1024;            // 1024*1024
  unsigned short* qkv    = Bt_o + (size_t)1024 * 1024;            // 8192*3072
  unsigned short* gatelin= qkv + (size_t)NTOK * 3072;             // 8192*1024
  unsigned short* ybuf   = gatelin + (size_t)NTOK * 1024;         // 8192*1024
  float* alphaF          = (float*)(ybuf + (size_t)NTOK * 1024);  // 8192*16
  float* betaF           = alphaF + (size_t)NTOK * 16;            // 8192*16
  unsigned short* zbuf   = xbf;  // alias: xbf dead after gate GEMM

  castx_k<<<NTOK * 1024 / 4 / 256, 256, 0, stream>>>(x, xbf, NTOK * 1024 / 4);
  dim3 tb(32, 8);
  transpose_k<<<dim3(32, 32), tb, 0, stream>>>(Wq, Bt_qkv, 1024, 1024);
  transpose_k<<<dim3(32, 32), tb, 0, stream>>>(Wk, Bt_qkv + (size_t)1024 * 1024, 1024, 1024);
  transpose_k<<<dim3(32, 32), tb, 0, stream>>>(Wv, Bt_qkv + (size_t)2048 * 1024, 1024, 1024);
  transpose_k<<<dim3(32, 32), tb, 0, stream>>>(Wg, Bt_g, 1024, 1024);
  transpose_k<<<dim3(32, 32), tb, 0, stream>>>(Wo, Bt_o, 1024, 1024);
  build_wabT<<<512, 256, 0, stream>>>(Wa, Wb, Bt_qkv + (size_t)3072 * 1024);

  gemm_bt<2><<<(NTOK / 128) * (NQKV / 128), 256, 0, stream>>>(
      xbf, Bt_qkv, qkv, NTOK, NQKV, 1024, ba, bb, alphaF, betaF);
  l2norm_k<<<65536, 256, 0, stream>>>(qkv);
  gemm_bt<0><<<(NTOK / 128) * (1024 / 128), 256, 0, stream>>>(
      xbf, Bt_g, gatelin, NTOK, 1024, 1024, nullptr, nullptr, nullptr, nullptr);
  scan_k<<<512, 64, 0, stream>>>(qkv, alphaF, betaF, ybuf);
  rmsgate_k<<<NTOK, 256, 0, stream>>>(ybuf, gatelin, gnorm, zbuf);
  gemm_bt<1><<<(NTOK / 128) * (1024 / 128), 256, 0, stream>>>(
      zbuf, Bt_o, out, NTOK, 1024, 1024, nullptr, nullptr, nullptr, nullptr);
}

// Round 6
// 705.563 us; speedup vs baseline: 3.3701x; 1.0810x over previous
//
#include <hip/hip_runtime.h>
#include <hip/hip_bf16.h>
#include <math.h>

typedef __attribute__((ext_vector_type(8))) short bf16x8s;
typedef __attribute__((ext_vector_type(4))) float f32x4;

#define SEQ 2048
#define NTOK 8192
#define NQKV 3200   // 3072 qkv + 32 ab + 96 zero-pad

static __device__ __forceinline__ float bf2f(unsigned short u) {
  union { unsigned int i; float f; } c; c.i = ((unsigned int)u) << 16; return c.f;
}
static __device__ __forceinline__ unsigned short f2bf(float f) {
  union { float f; unsigned int i; } c; c.f = f;
  unsigned int x = c.i;
  return (unsigned short)((x + 0x7FFFu + ((x >> 16) & 1u)) >> 16);
}

// ---- pure-VALU cross-lane reductions (DPP; no DS ops → off the LDS queue) ----
static __device__ __forceinline__ float red8(float x) {
  // sum across aligned 8-lane groups
  union { float f; int i; } c, d;
  c.f = x; d.i = __builtin_amdgcn_update_dpp(0, c.i, 0xB1, 0xF, 0xF, true); x += d.f;  // quad_perm [1,0,3,2]
  c.f = x; d.i = __builtin_amdgcn_update_dpp(0, c.i, 0x4E, 0xF, 0xF, true); x += d.f;  // quad_perm [2,3,0,1]
  c.f = x; d.i = __builtin_amdgcn_update_dpp(0, c.i, 0x141, 0xF, 0xF, true); x += d.f; // row_half_mirror (xor4 post-quad)
  return x;
}
static __device__ __forceinline__ float red16(float x) {
  // sum across aligned 16-lane groups
  union { float f; int i; } c, d;
  c.f = x; d.i = __builtin_amdgcn_update_dpp(0, c.i, 0xB1, 0xF, 0xF, true); x += d.f;
  c.f = x; d.i = __builtin_amdgcn_update_dpp(0, c.i, 0x4E, 0xF, 0xF, true); x += d.f;
  c.f = x; d.i = __builtin_amdgcn_update_dpp(0, c.i, 0x141, 0xF, 0xF, true); x += d.f;
  c.f = x; d.i = __builtin_amdgcn_update_dpp(0, c.i, 0x140, 0xF, 0xF, true); x += d.f; // row_mirror (xor8 post-half)
  return x;
}

// ---------------------------------------------------------------- x cast fp32 -> bf16
__global__ __launch_bounds__(256) void castx_k(const float* __restrict__ in,
                                               unsigned short* __restrict__ out, int n4) {
  int i = blockIdx.x * 256 + threadIdx.x;
  if (i >= n4) return;
  float4 v = ((const float4*)in)[i];
  ushort4 o;
  o.x = f2bf(v.x); o.y = f2bf(v.y); o.z = f2bf(v.z); o.w = f2bf(v.w);
  ((ushort4*)out)[i] = o;
}

// ---------------------------------------------------------------- transpose fp32 -> bf16
__global__ void transpose_k(const float* __restrict__ in,
                            unsigned short* __restrict__ out, int R, int C) {
  __shared__ unsigned short tile[32][33];
  int c0 = blockIdx.x * 32, r0 = blockIdx.y * 32;
  int tx = threadIdx.x, ty = threadIdx.y;
  for (int i = ty; i < 32; i += 8)
    tile[i][tx] = f2bf(in[(size_t)(r0 + i) * C + c0 + tx]);
  __syncthreads();
  for (int i = ty; i < 32; i += 8)
    out[(size_t)(c0 + i) * R + r0 + tx] = tile[tx][i];
}

// ---------------------------------------------------------------- Wab^T rows (bf16) + zero pad
__global__ void build_wabT(const float* __restrict__ Wa,
                           const float* __restrict__ Wb,
                           unsigned short* __restrict__ rows) {
  int i = blockIdx.x * 256 + threadIdx.x;  // 128 * 1024
  int j = i >> 10, k = i & 1023;
  float v = 0.f;
  if (j < 16) v = Wa[k * 16 + j];
  else if (j < 32) v = Wb[k * 16 + (j - 16)];
  rows[(size_t)j * 1024 + k] = f2bf(v);
}

// ---------------------------------------------------------------- MFMA GEMM (m97 staging)
// C[M,N] = A[M,K] * Bt[N,K]^T. MODE 0: bf16 out; 1: f32 out;
// 2: fused qkv: l2-normalize heads for cols<2048 (per-row 64-col norm, wave-local
//    16-lane DPP butterfly), bf16 out stride 3072, sigmoid alpha/beta for 3072..3103.
template<int MODE>
__global__ __launch_bounds__(256) void gemm_bt(const unsigned short* __restrict__ A,
                                               const unsigned short* __restrict__ Bt,
                                               void* __restrict__ Cv,
                                               int M, int N, int K,
                                               const float* __restrict__ ba,
                                               const float* __restrict__ bbp,
                                               float* __restrict__ alphaF,
                                               float* __restrict__ betaF) {
  __shared__ __align__(16) unsigned short As[128 * 32];
  __shared__ __align__(16) unsigned short Bs[128 * 32];
  int tiles_n = N >> 7;
  int tm = blockIdx.x / tiles_n, tn = blockIdx.x % tiles_n;
  int m0 = tm << 7, n0 = tn << 7;
  int tid = threadIdx.x;
  int wave = tid >> 6, lane = tid & 63;
  int wm = wave >> 1, wn = wave & 1;
  int r = lane & 15, qd = lane >> 4;
  int lr = lane >> 2, lc = lane & 3;

  f32x4 acc[4][4];
#pragma unroll
  for (int mi = 0; mi < 4; mi++)
#pragma unroll
    for (int ni = 0; ni < 4; ni++) acc[mi][ni] = (f32x4){0.f, 0.f, 0.f, 0.f};

  for (int k0 = 0; k0 < K; k0 += 32) {
#pragma unroll
    for (int gi = 0; gi < 2; ++gi) {
      int g = wave + gi * 4;
      int row = g * 16 + lr;
      const unsigned short* ga = A + (size_t)(m0 + row) * K + k0 + lc * 8;
      const unsigned short* gb = Bt + (size_t)(n0 + row) * K + k0 + lc * 8;
      __builtin_amdgcn_global_load_lds(
          (const __attribute__((address_space(1))) unsigned int*)ga,
          (__attribute__((address_space(3))) unsigned int*)(As + g * 512 + lane * 8),
          16, 0, 0);
      __builtin_amdgcn_global_load_lds(
          (const __attribute__((address_space(1))) unsigned int*)gb,
          (__attribute__((address_space(3))) unsigned int*)(Bs + g * 512 + lane * 8),
          16, 0, 0);
    }
    __syncthreads();
    bf16x8s af[4], bfr[4];
#pragma unroll
    for (int mi = 0; mi < 4; mi++)
      af[mi] = *(const bf16x8s*)&As[(wm * 64 + mi * 16 + r) * 32 + qd * 8];
#pragma unroll
    for (int ni = 0; ni < 4; ni++)
      bfr[ni] = *(const bf16x8s*)&Bs[(wn * 64 + ni * 16 + r) * 32 + qd * 8];
#pragma unroll
    for (int mi = 0; mi < 4; mi++)
#pragma unroll
      for (int ni = 0; ni < 4; ni++)
        acc[mi][ni] = __builtin_amdgcn_mfma_f32_16x16x32_bf16(af[mi], bfr[ni], acc[mi][ni], 0, 0, 0);
    __syncthreads();
  }

  bool qk = (MODE == 2) && (n0 < 2048);  // wave's 64-col block == one head
#pragma unroll
  for (int mi = 0; mi < 4; mi++) {
    f32x4 sc = (f32x4){1.f, 1.f, 1.f, 1.f};
    if (qk) {
      f32x4 ss = acc[mi][0] * acc[mi][0] + acc[mi][1] * acc[mi][1]
               + acc[mi][2] * acc[mi][2] + acc[mi][3] * acc[mi][3];
#pragma unroll
      for (int cc = 0; cc < 4; cc++) {
        float s = red16(ss[cc]);  // sum over r=0..15 lanes (x4 ni done above) = 64 cols
        sc[cc] = 1.f / fmaxf(sqrtf(s), 1e-12f);
      }
    }
#pragma unroll
    for (int ni = 0; ni < 4; ni++)
#pragma unroll
      for (int reg = 0; reg < 4; reg++) {
        int m = m0 + wm * 64 + mi * 16 + qd * 4 + reg;
        int n = n0 + wn * 64 + ni * 16 + r;
        float a = acc[mi][ni][reg];
        if (MODE == 0) ((unsigned short*)Cv)[(size_t)m * N + n] = f2bf(a);
        else if (MODE == 1) ((float*)Cv)[(size_t)m * N + n] = a;
        else {
          if (qk) a *= sc[reg];
          if (n < 3072) ((unsigned short*)Cv)[(size_t)m * 3072 + n] = f2bf(a);
          else if (n < 3104) {
            int j = n - 3072;
            float bias = (j < 16) ? ba[j] : bbp[j - 16];
            float s = 1.f / (1.f + expf(-(a + bias)));
            if (j < 16) alphaF[(size_t)m * 16 + j] = s;
            else        betaF[(size_t)m * 16 + (j - 16)] = s;
          }
        }
      }
  }
}

// ---------------------------------------------------------------- scan
// 512 blocks = (b*16+h)*8 + ec; block = 64 thr (ONE wave).
// lane = el*8+g: el = local e (e = ec*8+el), g = d-octet (8 d's).
// 8 fp32 S regs/lane. Reduction over g: 3 DPP adds (pure VALU — no DS on chain).
// Inner loop register-prefetches step t+1's LDS data; a/b/kq packed as float4.
#define TC 32
#define NCH (SEQ / TC)
#define LK 0
#define LQ 2048
#define LV 4096
#define LABQ 4352
#define SBUF 4480

static __device__ __forceinline__ void unpack8(uint4 v, float* f) {
  f[0] = bf2f((unsigned short)(v.x & 0xffff)); f[1] = bf2f((unsigned short)(v.x >> 16));
  f[2] = bf2f((unsigned short)(v.y & 0xffff)); f[3] = bf2f((unsigned short)(v.y >> 16));
  f[4] = bf2f((unsigned short)(v.z & 0xffff)); f[5] = bf2f((unsigned short)(v.z >> 16));
  f[6] = bf2f((unsigned short)(v.w & 0xffff)); f[7] = bf2f((unsigned short)(v.w >> 16));
}

struct Pref { uint4 k8[4], q8[4], v8; float ab; };

static __device__ __forceinline__ Pref scan_load(const unsigned short* __restrict__ qkv,
                                                 const float* __restrict__ alphaF,
                                                 const float* __restrict__ betaF,
                                                 int b, int h, int ec, int t0, int tid) {
  Pref p; p.v8 = (uint4){0, 0, 0, 0};
  const unsigned short* base = qkv + (size_t)(b * SEQ + t0) * 3072 + h * 64;
#pragma unroll
  for (int j = 0; j < 4; ++j) {
    int idx = j * 64 + tid;          // t*8 + seg
    int t = idx >> 3, seg = idx & 7;
    p.q8[j] = *(const uint4*)(base + (size_t)t * 3072 + seg * 8);
    p.k8[j] = *(const uint4*)(base + (size_t)t * 3072 + 1024 + seg * 8);
  }
  if (tid < 32) {
    p.v8 = *(const uint4*)(base + (size_t)tid * 3072 + 2048 + ec * 8);
    p.ab = alphaF[(size_t)(b * SEQ + t0 + tid) * 16 + h];
  } else {
    p.ab = betaF[(size_t)(b * SEQ + t0 + (tid - 32)) * 16 + h];
  }
  return p;
}

static __device__ __forceinline__ void scan_store(float* __restrict__ buf, const Pref& p, int tid) {
#pragma unroll
  for (int j = 0; j < 4; ++j) {
    int idx = j * 64 + tid;
    int t = idx >> 3, seg = idx & 7;
    float kf[8], qf[8];
    unpack8(p.k8[j], kf);
    unpack8(p.q8[j], qf);
    *(float4*)&buf[LK + t * 64 + seg * 8]     = (float4){kf[0], kf[1], kf[2], kf[3]};
    *(float4*)&buf[LK + t * 64 + seg * 8 + 4] = (float4){kf[4], kf[5], kf[6], kf[7]};
    *(float4*)&buf[LQ + t * 64 + seg * 8]     = (float4){qf[0], qf[1], qf[2], qf[3]};
    *(float4*)&buf[LQ + t * 64 + seg * 8 + 4] = (float4){qf[4], qf[5], qf[6], qf[7]};
    float s = kf[0]*qf[0] + kf[1]*qf[1] + kf[2]*qf[2] + kf[3]*qf[3]
            + kf[4]*qf[4] + kf[5]*qf[5] + kf[6]*qf[6] + kf[7]*qf[7];
    s = red8(s);                     // reduce over seg (= tid&7), pure VALU
    if ((tid & 7) == 0) buf[LABQ + t * 4 + 2] = s;   // kq_t
  }
  if (tid < 32) {
    float vf[8];
    unpack8(p.v8, vf);
    *(float4*)&buf[LV + tid * 8]     = (float4){vf[0], vf[1], vf[2], vf[3]};
    *(float4*)&buf[LV + tid * 8 + 4] = (float4){vf[4], vf[5], vf[6], vf[7]};
    buf[LABQ + tid * 4 + 0] = p.ab;                  // alpha_t
  } else {
    buf[LABQ + (tid - 32) * 4 + 1] = p.ab;           // beta_t
  }
}

__global__ __launch_bounds__(64) void scan_k(const unsigned short* __restrict__ qkv,
                                             const float* __restrict__ alphaF,
                                             const float* __restrict__ betaF,
                                             unsigned short* __restrict__ y) {
  __shared__ float sm[2 * SBUF];  // 35.8 KB
  int bh = blockIdx.x >> 3, ec = blockIdx.x & 7;
  int b = bh >> 4, h = bh & 15;
  int tid = threadIdx.x;
  int el = tid >> 3, g = tid & 7;

  float S0 = 0.f, S1 = 0.f, S2 = 0.f, S3 = 0.f;
  float S4 = 0.f, S5 = 0.f, S6 = 0.f, S7 = 0.f;

  Pref p = scan_load(qkv, alphaF, betaF, b, h, ec, 0, tid);
  scan_store(sm, p, tid);
  __syncthreads();

  unsigned short* yb = y + (size_t)(b * SEQ) * 1024 + h * 64 + ec * 8 + el;

  for (int c = 0; c < NCH; ++c) {
    if (c + 1 < NCH)
      p = scan_load(qkv, alphaF, betaF, b, h, ec, (c + 1) * TC, tid);

    const float* bb = sm + (c & 1) * SBUF;
    float4 k0 = *(const float4*)&bb[LK + g * 8];
    float4 k1 = *(const float4*)&bb[LK + g * 8 + 4];
    float4 q0 = *(const float4*)&bb[LQ + g * 8];
    float4 q1 = *(const float4*)&bb[LQ + g * 8 + 4];
    float ve = bb[LV + el];
    float4 abq = *(const float4*)&bb[LABQ];
#pragma unroll 4
    for (int t = 0; t < TC; ++t) {
      int tn = (t + 1 < TC) ? t + 1 : t;
      float4 nk0 = *(const float4*)&bb[LK + tn * 64 + g * 8];
      float4 nk1 = *(const float4*)&bb[LK + tn * 64 + g * 8 + 4];
      float4 nq0 = *(const float4*)&bb[LQ + tn * 64 + g * 8];
      float4 nq1 = *(const float4*)&bb[LQ + tn * 64 + g * 8 + 4];
      float nve = bb[LV + tn * 8 + el];
      float4 nabq = *(const float4*)&bb[LABQ + tn * 4];

      float at = abq.x, bt = abq.y, kqv = abq.z;
      float pr = ((S0*k0.x + S1*k0.y) + (S2*k0.z + S3*k0.w))
               + ((S4*k1.x + S5*k1.y) + (S6*k1.z + S7*k1.w));
      float qs = ((S0*q0.x + S1*q0.y) + (S2*q0.z + S3*q0.w))
               + ((S4*q1.x + S5*q1.y) + (S6*q1.z + S7*q1.w));
      pr = red8(pr);
      qs = red8(qs);
      float be = bt * (ve - pr);
      S0 = at*S0 + be*k0.x;  S1 = at*S1 + be*k0.y;
      S2 = at*S2 + be*k0.z;  S3 = at*S3 + be*k0.w;
      S4 = at*S4 + be*k1.x;  S5 = at*S5 + be*k1.y;
      S6 = at*S6 + be*k1.z;  S7 = at*S7 + be*k1.w;
      if (g == 0)
        yb[(size_t)(c * TC + t) * 1024] = f2bf(at * qs + be * kqv);

      k0 = nk0; k1 = nk1; q0 = nq0; q1 = nq1;
      ve = nve; abq = nabq;
    }
    if (c + 1 < NCH) {
      scan_store(sm + ((c + 1) & 1) * SBUF, p, tid);
      __syncthreads();
    }
  }
}

// ---------------------------------------------------------------- rmsnorm*gate
__global__ __launch_bounds__(256) void rmsgate_k(const unsigned short* __restrict__ y,
                                                 const unsigned short* __restrict__ gl,
                                                 const float* __restrict__ gnorm,
                                                 unsigned short* __restrict__ z) {
  __shared__ float red[4];
  int row = blockIdx.x, tid = threadIdx.x;
  size_t base = (size_t)row * 1024 + tid * 4;
  uint2 yv = *(const uint2*)&y[base];
  float f0 = bf2f((unsigned short)(yv.x & 0xffff)), f1 = bf2f((unsigned short)(yv.x >> 16));
  float f2 = bf2f((unsigned short)(yv.y & 0xffff)), f3 = bf2f((unsigned short)(yv.y >> 16));
  float ss = f0 * f0 + f1 * f1 + f2 * f2 + f3 * f3;
#pragma unroll
  for (int s = 1; s < 64; s <<= 1) ss += __shfl_xor(ss, s);
  if ((tid & 63) == 0) red[tid >> 6] = ss;
  __syncthreads();
  ss = red[0] + red[1] + red[2] + red[3];
  float rms = rsqrtf(ss * (1.0f / 1024.0f) + 1e-5f);
  uint2 gv = *(const uint2*)&gl[base];
  float4 gn = *(const float4*)&gnorm[tid * 4];
  float g[4] = {bf2f((unsigned short)(gv.x & 0xffff)), bf2f((unsigned short)(gv.x >> 16)),
                bf2f((unsigned short)(gv.y & 0xffff)), bf2f((unsigned short)(gv.y >> 16))};
  float gnv[4] = {gn.x, gn.y, gn.z, gn.w};
  float fv[4] = {f0, f1, f2, f3};
  unsigned short o[4];
#pragma unroll
  for (int jj = 0; jj < 4; jj++) {
    float gate = g[jj] / (1.f + expf(-g[jj]));  // silu
    o[jj] = f2bf(fv[jj] * rms * gnv[jj] * gate);
  }
  uint2 ov;
  ov.x = (unsigned int)o[0] | ((unsigned int)o[1] << 16);
  ov.y = (unsigned int)o[2] | ((unsigned int)o[3] << 16);
  *(uint2*)&z[base] = ov;
}

// ---------------------------------------------------------------- launch
extern "C" void kernel_launch(void* const* d_in, const int* in_sizes, int n_in,
                              void* d_out, int out_size, void* d_ws, size_t ws_size,
                              hipStream_t stream) {
  const float* x     = (const float*)d_in[0];
  const float* Wq    = (const float*)d_in[1];
  const float* Wk    = (const float*)d_in[2];
  const float* Wv    = (const float*)d_in[3];
  const float* Wa    = (const float*)d_in[4];
  const float* ba    = (const float*)d_in[5];
  const float* Wb    = (const float*)d_in[6];
  const float* bb    = (const float*)d_in[7];
  const float* Wg    = (const float*)d_in[8];
  const float* Wo    = (const float*)d_in[9];
  const float* gnorm = (const float*)d_in[10];
  float* out = (float*)d_out;

  unsigned short* xbf    = (unsigned short*)d_ws;                 // 8192*1024
  unsigned short* Bt_qkv = xbf + (size_t)NTOK * 1024;             // 3200*1024
  unsigned short* Bt_g   = Bt_qkv + (size_t)NQKV * 1024;          // 1024*1024
  unsigned short* Bt_o   = Bt_g + (size_t)1024 * 1024;            // 1024*1024
  unsigned short* qkv    = Bt_o + (size_t)1024 * 1024;            // 8192*3072
  unsigned short* gatelin= qkv + (size_t)NTOK * 3072;             // 8192*1024
  unsigned short* ybuf   = gatelin + (size_t)NTOK * 1024;         // 8192*1024
  float* alphaF          = (float*)(ybuf + (size_t)NTOK * 1024);  // 8192*16
  float* betaF           = alphaF + (size_t)NTOK * 16;            // 8192*16
  unsigned short* zbuf   = xbf;  // alias: xbf dead after gate GEMM

  castx_k<<<NTOK * 1024 / 4 / 256, 256, 0, stream>>>(x, xbf, NTOK * 1024 / 4);
  dim3 tb(32, 8);
  transpose_k<<<dim3(32, 32), tb, 0, stream>>>(Wq, Bt_qkv, 1024, 1024);
  transpose_k<<<dim3(32, 32), tb, 0, stream>>>(Wk, Bt_qkv + (size_t)1024 * 1024, 1024, 1024);
  transpose_k<<<dim3(32, 32), tb, 0, stream>>>(Wv, Bt_qkv + (size_t)2048 * 1024, 1024, 1024);
  transpose_k<<<dim3(32, 32), tb, 0, stream>>>(Wg, Bt_g, 1024, 1024);
  transpose_k<<<dim3(32, 32), tb, 0, stream>>>(Wo, Bt_o, 1024, 1024);
  build_wabT<<<512, 256, 0, stream>>>(Wa, Wb, Bt_qkv + (size_t)3072 * 1024);

  gemm_bt<2><<<(NTOK / 128) * (NQKV / 128), 256, 0, stream>>>(
      xbf, Bt_qkv, qkv, NTOK, NQKV, 1024, ba, bb, alphaF, betaF);
  gemm_bt<0><<<(NTOK / 128) * (1024 / 128), 256, 0, stream>>>(
      xbf, Bt_g, gatelin, NTOK, 1024, 1024, nullptr, nullptr, nullptr, nullptr);
  scan_k<<<512, 64, 0, stream>>>(qkv, alphaF, betaF, ybuf);
  rmsgate_k<<<NTOK, 256, 0, stream>>>(ybuf, gatelin, gnorm, zbuf);
  gemm_bt<1><<<(NTOK / 128) * (1024 / 128), 256, 0, stream>>>(
      zbuf, Bt_o, out, NTOK, 1024, 1024, nullptr, nullptr, nullptr, nullptr);
}

// Round 7
// 613.603 us; speedup vs baseline: 3.8752x; 1.1499x over previous
//
#include <hip/hip_runtime.h>
#include <hip/hip_bf16.h>
#include <math.h>

typedef __attribute__((ext_vector_type(8))) short bf16x8s;
typedef __attribute__((ext_vector_type(4))) float f32x4;

#define SEQ 2048
#define NTOK 8192
#define NQKV 3200   // 3072 qkv + 32 ab + 96 zero-pad

static __device__ __forceinline__ float bf2f(unsigned short u) {
  union { unsigned int i; float f; } c; c.i = ((unsigned int)u) << 16; return c.f;
}
static __device__ __forceinline__ unsigned short f2bf(float f) {
  union { float f; unsigned int i; } c; c.f = f;
  unsigned int x = c.i;
  return (unsigned short)((x + 0x7FFFu + ((x >> 16) & 1u)) >> 16);
}

// ---- pure-VALU cross-lane reductions (DPP; no DS ops) ----
static __device__ __forceinline__ float red8(float x) {
  union { float f; int i; } c, d;
  c.f = x; d.i = __builtin_amdgcn_update_dpp(0, c.i, 0xB1, 0xF, 0xF, true); x += d.f;  // quad_perm [1,0,3,2]
  c.f = x; d.i = __builtin_amdgcn_update_dpp(0, c.i, 0x4E, 0xF, 0xF, true); x += d.f;  // quad_perm [2,3,0,1]
  c.f = x; d.i = __builtin_amdgcn_update_dpp(0, c.i, 0x141, 0xF, 0xF, true); x += d.f; // row_half_mirror
  return x;
}
static __device__ __forceinline__ float red16(float x) {
  union { float f; int i; } c, d;
  c.f = x; d.i = __builtin_amdgcn_update_dpp(0, c.i, 0xB1, 0xF, 0xF, true); x += d.f;
  c.f = x; d.i = __builtin_amdgcn_update_dpp(0, c.i, 0x4E, 0xF, 0xF, true); x += d.f;
  c.f = x; d.i = __builtin_amdgcn_update_dpp(0, c.i, 0x141, 0xF, 0xF, true); x += d.f;
  c.f = x; d.i = __builtin_amdgcn_update_dpp(0, c.i, 0x140, 0xF, 0xF, true); x += d.f; // row_mirror
  return x;
}

// ---------------------------------------------------------------- x cast fp32 -> bf16
__global__ __launch_bounds__(256) void castx_k(const float* __restrict__ in,
                                               unsigned short* __restrict__ out, int n4) {
  int i = blockIdx.x * 256 + threadIdx.x;
  if (i >= n4) return;
  float4 v = ((const float4*)in)[i];
  ushort4 o;
  o.x = f2bf(v.x); o.y = f2bf(v.y); o.z = f2bf(v.z); o.w = f2bf(v.w);
  ((ushort4*)out)[i] = o;
}

// ---------------------------------------------------------------- transpose fp32 -> bf16
__global__ void transpose_k(const float* __restrict__ in,
                            unsigned short* __restrict__ out, int R, int C) {
  __shared__ unsigned short tile[32][33];
  int c0 = blockIdx.x * 32, r0 = blockIdx.y * 32;
  int tx = threadIdx.x, ty = threadIdx.y;
  for (int i = ty; i < 32; i += 8)
    tile[i][tx] = f2bf(in[(size_t)(r0 + i) * C + c0 + tx]);
  __syncthreads();
  for (int i = ty; i < 32; i += 8)
    out[(size_t)(c0 + i) * R + r0 + tx] = tile[tx][i];
}

// ---------------------------------------------------------------- Wab^T rows (bf16) + zero pad
__global__ void build_wabT(const float* __restrict__ Wa,
                           const float* __restrict__ Wb,
                           unsigned short* __restrict__ rows) {
  int i = blockIdx.x * 256 + threadIdx.x;  // 128 * 1024
  int j = i >> 10, k = i & 1023;
  float v = 0.f;
  if (j < 16) v = Wa[k * 16 + j];
  else if (j < 32) v = Wb[k * 16 + (j - 16)];
  rows[(size_t)j * 1024 + k] = f2bf(v);
}

// ---------------------------------------------------------------- MFMA GEMM (m97 staging)
// C[M,N] = A[M,K] * Bt[N,K]^T. MODE 0: bf16 out; 1: f32 out;
// 2: fused qkv: per-head l2norm for cols<2048, sigmoid alpha/beta for 3072..3103.
template<int MODE>
__global__ __launch_bounds__(256) void gemm_bt(const unsigned short* __restrict__ A,
                                               const unsigned short* __restrict__ Bt,
                                               void* __restrict__ Cv,
                                               int M, int N, int K,
                                               const float* __restrict__ ba,
                                               const float* __restrict__ bbp,
                                               float* __restrict__ alphaF,
                                               float* __restrict__ betaF) {
  __shared__ __align__(16) unsigned short As[128 * 32];
  __shared__ __align__(16) unsigned short Bs[128 * 32];
  int tiles_n = N >> 7;
  int tm = blockIdx.x / tiles_n, tn = blockIdx.x % tiles_n;
  int m0 = tm << 7, n0 = tn << 7;
  int tid = threadIdx.x;
  int wave = tid >> 6, lane = tid & 63;
  int wm = wave >> 1, wn = wave & 1;
  int r = lane & 15, qd = lane >> 4;
  int lr = lane >> 2, lc = lane & 3;

  f32x4 acc[4][4];
#pragma unroll
  for (int mi = 0; mi < 4; mi++)
#pragma unroll
    for (int ni = 0; ni < 4; ni++) acc[mi][ni] = (f32x4){0.f, 0.f, 0.f, 0.f};

  for (int k0 = 0; k0 < K; k0 += 32) {
#pragma unroll
    for (int gi = 0; gi < 2; ++gi) {
      int g = wave + gi * 4;
      int row = g * 16 + lr;
      const unsigned short* ga = A + (size_t)(m0 + row) * K + k0 + lc * 8;
      const unsigned short* gb = Bt + (size_t)(n0 + row) * K + k0 + lc * 8;
      __builtin_amdgcn_global_load_lds(
          (const __attribute__((address_space(1))) unsigned int*)ga,
          (__attribute__((address_space(3))) unsigned int*)(As + g * 512 + lane * 8),
          16, 0, 0);
      __builtin_amdgcn_global_load_lds(
          (const __attribute__((address_space(1))) unsigned int*)gb,
          (__attribute__((address_space(3))) unsigned int*)(Bs + g * 512 + lane * 8),
          16, 0, 0);
    }
    __syncthreads();
    bf16x8s af[4], bfr[4];
#pragma unroll
    for (int mi = 0; mi < 4; mi++)
      af[mi] = *(const bf16x8s*)&As[(wm * 64 + mi * 16 + r) * 32 + qd * 8];
#pragma unroll
    for (int ni = 0; ni < 4; ni++)
      bfr[ni] = *(const bf16x8s*)&Bs[(wn * 64 + ni * 16 + r) * 32 + qd * 8];
#pragma unroll
    for (int mi = 0; mi < 4; mi++)
#pragma unroll
      for (int ni = 0; ni < 4; ni++)
        acc[mi][ni] = __builtin_amdgcn_mfma_f32_16x16x32_bf16(af[mi], bfr[ni], acc[mi][ni], 0, 0, 0);
    __syncthreads();
  }

  bool qk = (MODE == 2) && (n0 < 2048);  // wave's 64-col block == one head
#pragma unroll
  for (int mi = 0; mi < 4; mi++) {
    f32x4 sc = (f32x4){1.f, 1.f, 1.f, 1.f};
    if (qk) {
      f32x4 ss = acc[mi][0] * acc[mi][0] + acc[mi][1] * acc[mi][1]
               + acc[mi][2] * acc[mi][2] + acc[mi][3] * acc[mi][3];
#pragma unroll
      for (int cc = 0; cc < 4; cc++) {
        float s = red16(ss[cc]);
        sc[cc] = 1.f / fmaxf(sqrtf(s), 1e-12f);
      }
    }
#pragma unroll
    for (int ni = 0; ni < 4; ni++)
#pragma unroll
      for (int reg = 0; reg < 4; reg++) {
        int m = m0 + wm * 64 + mi * 16 + qd * 4 + reg;
        int n = n0 + wn * 64 + ni * 16 + r;
        float a = acc[mi][ni][reg];
        if (MODE == 0) ((unsigned short*)Cv)[(size_t)m * N + n] = f2bf(a);
        else if (MODE == 1) ((float*)Cv)[(size_t)m * N + n] = a;
        else {
          if (qk) a *= sc[reg];
          if (n < 3072) ((unsigned short*)Cv)[(size_t)m * 3072 + n] = f2bf(a);
          else if (n < 3104) {
            int j = n - 3072;
            float bias = (j < 16) ? ba[j] : bbp[j - 16];
            float s = 1.f / (1.f + expf(-(a + bias)));
            if (j < 16) alphaF[(size_t)m * 16 + j] = s;
            else        betaF[(size_t)m * 16 + (j - 16)] = s;
          }
        }
      }
  }
}

// ---------------------------------------------------------------- scan
// 512 blocks = (b*16+h)*8 + ec; block = 64 thr (ONE wave).
// lane = el*8+g: el = local e, g = d-octet. 8 fp32 S regs/lane.
// Inner 32-step loop FULLY UNROLLED: LDS addresses become immediates, register
// double-buffer (prefetch distance ~2 iters), y outputs buffered per chunk.
#define TC 32
#define NCH (SEQ / TC)
#define LK 0
#define LQ 2048
#define LV 4096
#define LABQ 4352
#define SBUF 4480

static __device__ __forceinline__ void unpack8(uint4 v, float* f) {
  f[0] = bf2f((unsigned short)(v.x & 0xffff)); f[1] = bf2f((unsigned short)(v.x >> 16));
  f[2] = bf2f((unsigned short)(v.y & 0xffff)); f[3] = bf2f((unsigned short)(v.y >> 16));
  f[4] = bf2f((unsigned short)(v.z & 0xffff)); f[5] = bf2f((unsigned short)(v.z >> 16));
  f[6] = bf2f((unsigned short)(v.w & 0xffff)); f[7] = bf2f((unsigned short)(v.w >> 16));
}

struct Pref { uint4 k8[4], q8[4], v8; float ab; };

static __device__ __forceinline__ Pref scan_load(const unsigned short* __restrict__ qkv,
                                                 const float* __restrict__ alphaF,
                                                 const float* __restrict__ betaF,
                                                 int b, int h, int ec, int t0, int tid) {
  Pref p; p.v8 = (uint4){0, 0, 0, 0};
  const unsigned short* base = qkv + (size_t)(b * SEQ + t0) * 3072 + h * 64;
#pragma unroll
  for (int j = 0; j < 4; ++j) {
    int idx = j * 64 + tid;          // t*8 + seg
    int t = idx >> 3, seg = idx & 7;
    p.q8[j] = *(const uint4*)(base + (size_t)t * 3072 + seg * 8);
    p.k8[j] = *(const uint4*)(base + (size_t)t * 3072 + 1024 + seg * 8);
  }
  if (tid < 32) {
    p.v8 = *(const uint4*)(base + (size_t)tid * 3072 + 2048 + ec * 8);
    p.ab = alphaF[(size_t)(b * SEQ + t0 + tid) * 16 + h];
  } else {
    p.ab = betaF[(size_t)(b * SEQ + t0 + (tid - 32)) * 16 + h];
  }
  return p;
}

static __device__ __forceinline__ void scan_store(float* __restrict__ buf, const Pref& p, int tid) {
#pragma unroll
  for (int j = 0; j < 4; ++j) {
    int idx = j * 64 + tid;
    int t = idx >> 3, seg = idx & 7;
    float kf[8], qf[8];
    unpack8(p.k8[j], kf);
    unpack8(p.q8[j], qf);
    *(float4*)&buf[LK + t * 64 + seg * 8]     = (float4){kf[0], kf[1], kf[2], kf[3]};
    *(float4*)&buf[LK + t * 64 + seg * 8 + 4] = (float4){kf[4], kf[5], kf[6], kf[7]};
    *(float4*)&buf[LQ + t * 64 + seg * 8]     = (float4){qf[0], qf[1], qf[2], qf[3]};
    *(float4*)&buf[LQ + t * 64 + seg * 8 + 4] = (float4){qf[4], qf[5], qf[6], qf[7]};
    float s = kf[0]*qf[0] + kf[1]*qf[1] + kf[2]*qf[2] + kf[3]*qf[3]
            + kf[4]*qf[4] + kf[5]*qf[5] + kf[6]*qf[6] + kf[7]*qf[7];
    s = red8(s);
    if ((tid & 7) == 0) buf[LABQ + t * 4 + 2] = s;   // kq_t
  }
  if (tid < 32) {
    float vf[8];
    unpack8(p.v8, vf);
    *(float4*)&buf[LV + tid * 8]     = (float4){vf[0], vf[1], vf[2], vf[3]};
    *(float4*)&buf[LV + tid * 8 + 4] = (float4){vf[4], vf[5], vf[6], vf[7]};
    buf[LABQ + tid * 4 + 0] = p.ab;                  // alpha_t
  } else {
    buf[LABQ + (tid - 32) * 4 + 1] = p.ab;           // beta_t
  }
}

__global__ __launch_bounds__(64) void scan_k(const unsigned short* __restrict__ qkv,
                                             const float* __restrict__ alphaF,
                                             const float* __restrict__ betaF,
                                             unsigned short* __restrict__ y) {
  __shared__ float sm[2 * SBUF];  // 35.8 KB
  int bh = blockIdx.x >> 3, ec = blockIdx.x & 7;
  int b = bh >> 4, h = bh & 15;
  int tid = threadIdx.x;
  int el = tid >> 3, g = tid & 3 + 0;  // placeholder; fixed below
  g = tid & 7;

  float S0 = 0.f, S1 = 0.f, S2 = 0.f, S3 = 0.f;
  float S4 = 0.f, S5 = 0.f, S6 = 0.f, S7 = 0.f;

  Pref p = scan_load(qkv, alphaF, betaF, b, h, ec, 0, tid);
  scan_store(sm, p, tid);
  __syncthreads();

  unsigned short* yb = y + (size_t)(b * SEQ) * 1024 + h * 64 + ec * 8 + el;

  for (int c = 0; c < NCH; ++c) {
    if (c + 1 < NCH)
      p = scan_load(qkv, alphaF, betaF, b, h, ec, (c + 1) * TC, tid);

    const float* bb = sm + (c & 1) * SBUF;
    // 2-deep register buffers; peel t=0,1
    float4 rk0[2], rk1[2], rq0[2], rq1[2], rabq[2];
    float rve[2];
#pragma unroll
    for (int i = 0; i < 2; ++i) {
      rk0[i] = *(const float4*)&bb[LK + i * 64 + g * 8];
      rk1[i] = *(const float4*)&bb[LK + i * 64 + g * 8 + 4];
      rq0[i] = *(const float4*)&bb[LQ + i * 64 + g * 8];
      rq1[i] = *(const float4*)&bb[LQ + i * 64 + g * 8 + 4];
      rve[i] = bb[LV + i * 8 + el];
      rabq[i] = *(const float4*)&bb[LABQ + i * 4];
    }
    float yo[TC];
#pragma unroll
    for (int t = 0; t < TC; ++t) {
      const int sl = t & 1;
      float4 k0 = rk0[sl], k1 = rk1[sl], q0 = rq0[sl], q1 = rq1[sl];
      float4 abq = rabq[sl];
      float ve = rve[sl];
      float at = abq.x, bt = abq.y, kqv = abq.z;
      float btve = bt * ve;
      float pr = ((S0*k0.x + S1*k0.y) + (S2*k0.z + S3*k0.w))
               + ((S4*k1.x + S5*k1.y) + (S6*k1.z + S7*k1.w));
      float qs = ((S0*q0.x + S1*q0.y) + (S2*q0.z + S3*q0.w))
               + ((S4*q1.x + S5*q1.y) + (S6*q1.z + S7*q1.w));
      pr = red8(pr);
      qs = red8(qs);
      float be = btve - bt * pr;
      S0 = at*S0 + be*k0.x;  S1 = at*S1 + be*k0.y;
      S2 = at*S2 + be*k0.z;  S3 = at*S3 + be*k0.w;
      S4 = at*S4 + be*k1.x;  S5 = at*S5 + be*k1.y;
      S6 = at*S6 + be*k1.z;  S7 = at*S7 + be*k1.w;
      yo[t] = at * qs + be * kqv;
      if (t + 2 < TC) {
        const int tn = t + 2;
        rk0[sl] = *(const float4*)&bb[LK + tn * 64 + g * 8];
        rk1[sl] = *(const float4*)&bb[LK + tn * 64 + g * 8 + 4];
        rq0[sl] = *(const float4*)&bb[LQ + tn * 64 + g * 8];
        rq1[sl] = *(const float4*)&bb[LQ + tn * 64 + g * 8 + 4];
        rve[sl] = bb[LV + tn * 8 + el];
        rabq[sl] = *(const float4*)&bb[LABQ + tn * 4];
      }
    }
    if (g == 0) {
#pragma unroll
      for (int t = 0; t < TC; ++t)
        yb[(size_t)(c * TC + t) * 1024] = f2bf(yo[t]);
    }
    if (c + 1 < NCH) {
      scan_store(sm + ((c + 1) & 1) * SBUF, p, tid);
      __syncthreads();
    }
  }
}

// ---------------------------------------------------------------- rmsnorm*gate
__global__ __launch_bounds__(256) void rmsgate_k(const unsigned short* __restrict__ y,
                                                 const unsigned short* __restrict__ gl,
                                                 const float* __restrict__ gnorm,
                                                 unsigned short* __restrict__ z) {
  __shared__ float red[4];
  int row = blockIdx.x, tid = threadIdx.x;
  size_t base = (size_t)row * 1024 + tid * 4;
  uint2 yv = *(const uint2*)&y[base];
  float f0 = bf2f((unsigned short)(yv.x & 0xffff)), f1 = bf2f((unsigned short)(yv.x >> 16));
  float f2 = bf2f((unsigned short)(yv.y & 0xffff)), f3 = bf2f((unsigned short)(yv.y >> 16));
  float ss = f0 * f0 + f1 * f1 + f2 * f2 + f3 * f3;
#pragma unroll
  for (int s = 1; s < 64; s <<= 1) ss += __shfl_xor(ss, s);
  if ((tid & 63) == 0) red[tid >> 6] = ss;
  __syncthreads();
  ss = red[0] + red[1] + red[2] + red[3];
  float rms = rsqrtf(ss * (1.0f / 1024.0f) + 1e-5f);
  uint2 gv = *(const uint2*)&gl[base];
  float4 gn = *(const float4*)&gnorm[tid * 4];
  float g[4] = {bf2f((unsigned short)(gv.x & 0xffff)), bf2f((unsigned short)(gv.x >> 16)),
                bf2f((unsigned short)(gv.y & 0xffff)), bf2f((unsigned short)(gv.y >> 16))};
  float gnv[4] = {gn.x, gn.y, gn.z, gn.w};
  float fv[4] = {f0, f1, f2, f3};
  unsigned short o[4];
#pragma unroll
  for (int jj = 0; jj < 4; jj++) {
    float gate = g[jj] / (1.f + expf(-g[jj]));  // silu
    o[jj] = f2bf(fv[jj] * rms * gnv[jj] * gate);
  }
  uint2 ov;
  ov.x = (unsigned int)o[0] | ((unsigned int)o[1] << 16);
  ov.y = (unsigned int)o[2] | ((unsigned int)o[3] << 16);
  *(uint2*)&z[base] = ov;
}

// ---------------------------------------------------------------- launch
extern "C" void kernel_launch(void* const* d_in, const int* in_sizes, int n_in,
                              void* d_out, int out_size, void* d_ws, size_t ws_size,
                              hipStream_t stream) {
  const float* x     = (const float*)d_in[0];
  const float* Wq    = (const float*)d_in[1];
  const float* Wk    = (const float*)d_in[2];
  const float* Wv    = (const float*)d_in[3];
  const float* Wa    = (const float*)d_in[4];
  const float* ba    = (const float*)d_in[5];
  const float* Wb    = (const float*)d_in[6];
  const float* bb    = (const float*)d_in[7];
  const float* Wg    = (const float*)d_in[8];
  const float* Wo    = (const float*)d_in[9];
  const float* gnorm = (const float*)d_in[10];
  float* out = (float*)d_out;

  unsigned short* xbf    = (unsigned short*)d_ws;                 // 8192*1024
  unsigned short* Bt_qkv = xbf + (size_t)NTOK * 1024;             // 3200*1024
  unsigned short* Bt_g   = Bt_qkv + (size_t)NQKV * 1024;          // 1024*1024
  unsigned short* Bt_o   = Bt_g + (size_t)1024 * 1024;            // 1024*1024
  unsigned short* qkv    = Bt_o + (size_t)1024 * 1024;            // 8192*3072
  unsigned short* gatelin= qkv + (size_t)NTOK * 3072;             // 8192*1024
  unsigned short* ybuf   = gatelin + (size_t)NTOK * 1024;         // 8192*1024
  float* alphaF          = (float*)(ybuf + (size_t)NTOK * 1024);  // 8192*16
  float* betaF           = alphaF + (size_t)NTOK * 16;            // 8192*16
  unsigned short* zbuf   = xbf;  // alias: xbf dead after gate GEMM

  castx_k<<<NTOK * 1024 / 4 / 256, 256, 0, stream>>>(x, xbf, NTOK * 1024 / 4);
  dim3 tb(32, 8);
  transpose_k<<<dim3(32, 32), tb, 0, stream>>>(Wq, Bt_qkv, 1024, 1024);
  transpose_k<<<dim3(32, 32), tb, 0, stream>>>(Wk, Bt_qkv + (size_t)1024 * 1024, 1024, 1024);
  transpose_k<<<dim3(32, 32), tb, 0, stream>>>(Wv, Bt_qkv + (size_t)2048 * 1024, 1024, 1024);
  transpose_k<<<dim3(32, 32), tb, 0, stream>>>(Wg, Bt_g, 1024, 1024);
  transpose_k<<<dim3(32, 32), tb, 0, stream>>>(Wo, Bt_o, 1024, 1024);
  build_wabT<<<512, 256, 0, stream>>>(Wa, Wb, Bt_qkv + (size_t)3072 * 1024);

  gemm_bt<2><<<(NTOK / 128) * (NQKV / 128), 256, 0, stream>>>(
      xbf, Bt_qkv, qkv, NTOK, NQKV, 1024, ba, bb, alphaF, betaF);
  gemm_bt<0><<<(NTOK / 128) * (1024 / 128), 256, 0, stream>>>(
      xbf, Bt_g, gatelin, NTOK, 1024, 1024, nullptr, nullptr, nullptr, nullptr);
  scan_k<<<512, 64, 0, stream>>>(qkv, alphaF, betaF, ybuf);
  rmsgate_k<<<NTOK, 256, 0, stream>>>(ybuf, gatelin, gnorm, zbuf);
  gemm_bt<1><<<(NTOK / 128) * (1024 / 128), 256, 0, stream>>>(
      zbuf, Bt_o, out, NTOK, 1024, 1024, nullptr, nullptr, nullptr, nullptr);
}